// Round 8
// baseline (779.951 us; speedup 1.0000x reference)
//
#include <hip/hip_runtime.h>
#include <hip/hip_bf16.h>

#define NN 50000
#define NE 800000
#define IND 128
#define NH 8

typedef __hip_bfloat16 bf16;
typedef __attribute__((ext_vector_type(8))) short short8;
typedef __attribute__((ext_vector_type(8))) __bf16 bf16x8;
typedef __attribute__((ext_vector_type(4))) float floatx4;

// float -> bf16 bits, round-to-nearest-even (finite inputs only)
static __device__ __forceinline__ short f2bf_bits(float f) {
    unsigned u = __float_as_uint(f);
    u = (u + 0x7fffu + ((u >> 16) & 1u)) >> 16;
    return (short)u;
}
static __device__ __forceinline__ float bf2f(bf16 v) { return __bfloat162float(v); }

// ---------------- CSR build ----------------
__global__ void zero_int_kernel(int* p, int n) {
    int i = blockIdx.x * 256 + threadIdx.x;
    if (i < n) p[i] = 0;
}
__global__ void hist_kernel(const int* __restrict__ edst, int* __restrict__ cnt, int e) {
    int i = blockIdx.x * 256 + threadIdx.x;
    if (i < e) atomicAdd(&cnt[edst[i]], 1);
}
__global__ __launch_bounds__(1024) void scan_kernel(const int* __restrict__ cnt,
        int* __restrict__ rowptr, int* __restrict__ cursor, float* __restrict__ dinv) {
    __shared__ int psum[1024];
    const int tid = threadIdx.x;
    const int per = (NN + 1023) / 1024;
    const int base = tid * per;
    int s = 0;
    for (int i = 0; i < per; ++i) {
        int idx = base + i;
        if (idx < NN) s += cnt[idx];
    }
    psum[tid] = s;
    __syncthreads();
    for (int off = 1; off < 1024; off <<= 1) {
        int v = 0;
        if (tid >= off) v = psum[tid - off];
        __syncthreads();
        if (tid >= off) psum[tid] += v;
        __syncthreads();
    }
    int run = psum[tid] - s;
    for (int i = 0; i < per; ++i) {
        int idx = base + i;
        if (idx < NN) {
            rowptr[idx] = run;
            cursor[idx] = run;
            int c = cnt[idx];
            dinv[idx] = rsqrtf((float)c + 1.f);
            run += c;
        }
    }
    if (tid == 0) rowptr[NN] = NE;
}
__global__ void scatter_kernel(const int* __restrict__ esrc, const int* __restrict__ edst,
        int* __restrict__ cursor, int* __restrict__ csrc, int e) {
    int i = blockIdx.x * 256 + threadIdx.x;
    if (i >= e) return;
    int d = edst[i];
    int pos = atomicAdd(&cursor[d], 1);
    csrc[pos] = esrc[i];
}

// ---------------- MFMA matmul: C[n,M] = A[n,K] @ W[K,M] ----------------
// K-chunked LDS staging (BK=128). W fp32; A fp32 or bf16 (ABF16).
// EPI 0: raw fp32; 1: plain bf16; 2: bf16 relu(v*0.125+bias[col]).
// Fragment layouts verified R6.
template<int K, bool ABF16, int EPI>
__global__ __launch_bounds__(256) void mm_kernel(const void* __restrict__ A,
        const float* __restrict__ W, void* __restrict__ C,
        const float* __restrict__ bias, int nrows, int M) {
    constexpr int BK = (K > 128) ? 128 : K;
    __shared__ __align__(16) short Alds[64][BK + 8];
    __shared__ __align__(16) short Wlds[64][BK + 8];   // transposed: Wlds[m][k]
    const int row0 = blockIdx.x * 64;
    const int m0   = blockIdx.y * 64;
    const int tid  = threadIdx.x;
    const int lane = tid & 63, wave = tid >> 6;
    const int lr = lane & 15, q = lane >> 4;
    const int rw = wave * 16;
    floatx4 acc[4] = {};

    for (int kc = 0; kc < K; kc += BK) {
        if (kc) __syncthreads();
        constexpr int KB = BK / 8;
        for (int i = tid; i < 64 * KB; i += 256) {
            int r = i / KB, kb = i % KB;
            int row = row0 + r;
            short8 v = {0, 0, 0, 0, 0, 0, 0, 0};
            if (row < nrows) {
                if (ABF16) {
                    v = *(const short8*)((const short*)A + (long)row * K + kc + kb * 8);
                } else {
                    const float* ap = (const float*)A + (long)row * K + kc + kb * 8;
                    floatx4 va = *(const floatx4*)ap;
                    floatx4 vb = *(const floatx4*)(ap + 4);
#pragma unroll
                    for (int j = 0; j < 4; ++j) { v[j] = f2bf_bits(va[j]); v[4 + j] = f2bf_bits(vb[j]); }
                }
            }
            *(short8*)&Alds[r][kb * 8] = v;
        }
        for (int i = tid; i < BK * 64; i += 256) {
            int k = i >> 6, m = i & 63;
            Wlds[m][k] = (m0 + m < M) ? f2bf_bits(W[(long)(kc + k) * M + m0 + m]) : (short)0;
        }
        __syncthreads();
#pragma unroll
        for (int k0 = 0; k0 < BK; k0 += 32) {
            bf16x8 a = __builtin_bit_cast(bf16x8, *(const short8*)&Alds[rw + lr][k0 + q * 8]);
#pragma unroll
            for (int c = 0; c < 4; ++c) {
                bf16x8 b = __builtin_bit_cast(bf16x8, *(const short8*)&Wlds[c * 16 + lr][k0 + q * 8]);
                acc[c] = __builtin_amdgcn_mfma_f32_16x16x32_bf16(a, b, acc[c], 0, 0, 0);
            }
        }
    }
#pragma unroll
    for (int c = 0; c < 4; ++c)
#pragma unroll
        for (int r = 0; r < 4; ++r) {
            int row = row0 + rw + q * 4 + r;
            int col = m0 + c * 16 + lr;
            if (row < nrows && col < M) {
                long o = (long)row * M + col;
                float v = acc[c][r];
                if (EPI == 0) ((float*)C)[o] = v;
                else if (EPI == 1) ((bf16*)C)[o] = __float2bfloat16(v);
                else {
                    v = v * 0.125f + bias[col];
                    ((bf16*)C)[o] = __float2bfloat16(fmaxf(v, 0.f));
                }
            }
        }
}

// ---------------- fused GCN aggregate + bias + BN + ReLU (CSR, no atomics) ----------------
__global__ __launch_bounds__(256) void gcn_fused_kernel(const int* __restrict__ rowptr,
        const int* __restrict__ csrc, const float* __restrict__ dinv,
        const bf16* __restrict__ hin, const float* __restrict__ b,
        const float* __restrict__ gamma, const float* __restrict__ beta,
        const float* __restrict__ mean, const float* __restrict__ var,
        bf16* __restrict__ actout) {
    const int node = blockIdx.x * 4 + (threadIdx.x >> 6);
    if (node >= NN) return;
    const int lane = threadIdx.x & 63;
    const int beg = rowptr[node], end = rowptr[node + 1];
    const float di = dinv[node];
    float acc = di * bf2f(hin[(long)node * 64 + lane]);   // self
    int ei = beg;
    for (; ei + 4 <= end; ei += 4) {
        int s0 = csrc[ei], s1 = csrc[ei + 1], s2 = csrc[ei + 2], s3 = csrc[ei + 3];
        float w0 = dinv[s0], w1 = dinv[s1], w2 = dinv[s2], w3 = dinv[s3];
        float h0 = bf2f(hin[(long)s0 * 64 + lane]);
        float h1 = bf2f(hin[(long)s1 * 64 + lane]);
        float h2 = bf2f(hin[(long)s2 * 64 + lane]);
        float h3 = bf2f(hin[(long)s3 * 64 + lane]);
        acc += w0 * h0 + w1 * h1 + w2 * h2 + w3 * h3;
    }
    for (; ei < end; ++ei) {
        int s = csrc[ei];
        acc += dinv[s] * bf2f(hin[(long)s * 64 + lane]);
    }
    float x = acc * di + b[lane];
    x = (x - mean[lane]) * rsqrtf(var[lane] + 1e-5f) * gamma[lane] + beta[lane];
    actout[(long)node * 64 + lane] = __float2bfloat16(fmaxf(x, 0.f));
}

// ---------------- attention prep: project a-vectors through W ----------------
// was[h*64+c] = sum_{c'} W[c][h*C+c'] * asrc[h*C+c']  (W is [64][8*C] row-major)
template<int C>
__global__ void proj_aw_kernel(const float* __restrict__ W, const float* __restrict__ as,
        const float* __restrict__ ad, float* __restrict__ was, float* __restrict__ wad) {
    int idx = blockIdx.x * 256 + threadIdx.x;
    if (idx >= 512) return;
    int h = idx >> 6, c = idx & 63;
    const float* wrow = W + (long)c * (NH * C) + h * C;
    float s = 0.f, d = 0.f;
    for (int cc = 0; cc < C; ++cc) {
        float w = wrow[cc];
        s += w * as[h * C + cc];
        d += w * ad[h * C + cc];
    }
    was[idx] = s; wad[idx] = d;
}
// wp[(h*64+c)*C + c'] = W[c][h*C+c']
template<int C>
__global__ void reshape_w_kernel(const float* __restrict__ W, float* __restrict__ wp) {
    int idx = blockIdx.x * 256 + threadIdx.x;
    if (idx >= 512 * C) return;
    int kk = idx / C, cp = idx % C;
    int h = kk >> 6, c = kk & 63;
    wp[idx] = W[(long)c * (NH * C) + h * C + cp];
}
// es[n,h] = <act[n,:], was[h,:]>
__global__ void scores_kernel(const bf16* __restrict__ actb, const float* __restrict__ was,
        const float* __restrict__ wad, float* __restrict__ es, float* __restrict__ ed, int n) {
    int idx = blockIdx.x * 256 + threadIdx.x;
    if (idx >= n * NH) return;
    int nd = idx >> 3, h = idx & 7;
    const bf16* ap = actb + (long)nd * 64;
    float s = 0.f, d = 0.f;
    for (int c = 0; c < 64; ++c) {
        float v = bf2f(ap[c]);
        s += v * was[h * 64 + c];
        d += v * wad[h * 64 + c];
    }
    es[idx] = s; ed[idx] = d;
}

// ---------------- GAT aggregation in act-space (CSR, no atomics) ----------------
// one wave per dst. Phase A: online softmax per head (lanes=(slot,h), butterfly over slots).
// Phase B: per edge gather act[s] row once (128 B), accumulate 8 head-accumulators.
// agg[d][h][c] = sum_s alpha(d,s,h) * act[s][c]   (incl. self-loop), bf16 out.
__global__ __launch_bounds__(256) void gat_agg_kernel(const int* __restrict__ rowptr,
        const int* __restrict__ csrc, const float* __restrict__ es, const float* __restrict__ ed,
        const bf16* __restrict__ actb, bf16* __restrict__ agg) {
    const int node = blockIdx.x * 4 + (threadIdx.x >> 6);
    if (node >= NN) return;
    const int lane = threadIdx.x & 63;
    const int h = lane & 7, slot = lane >> 3;
    const int beg = rowptr[node], end = rowptr[node + 1];
    const float edr = ed[node * NH + h];

    float selfe = es[node * NH + h] + edr;
    selfe = selfe > 0.f ? selfe : 0.2f * selfe;

    // ---- Phase A: online softmax (m, den) ----
    float m, den;
    if (slot == 0) { m = selfe; den = 1.f; }
    else           { m = -3e38f; den = 0.f; }
    for (int base = beg; base < end; base += 8) {
        int ei = base + slot;
        float e = -3e38f;
        if (ei < end) {
            int s = csrc[ei];
            e = es[s * NH + h] + edr;
            e = e > 0.f ? e : 0.2f * e;
        }
        float mn = fmaxf(m, e);
        den = den * __expf(m - mn) + ((ei < end) ? __expf(e - mn) : 0.f);
        m = mn;
    }
#pragma unroll
    for (int off = 8; off < 64; off <<= 1) {
        float m2 = __shfl_xor(m, off), d2 = __shfl_xor(den, off);
        float mn = fmaxf(m, m2);
        den = den * __expf(m - mn) + d2 * __expf(m2 - mn);
        m = mn;
    }
    const float invden = 1.f / (den + 1e-16f);

    // ---- Phase B ----
    float acc[NH] = {0.f, 0.f, 0.f, 0.f, 0.f, 0.f, 0.f, 0.f};
    for (int base = beg; base < end; base += 8) {
        int ei = base + slot;
        float al = 0.f; int sl = 0;
        if (ei < end) {
            sl = csrc[ei];
            float e = es[sl * NH + h] + edr;
            e = e > 0.f ? e : 0.2f * e;
            al = __expf(e - m) * invden;
        }
        int ecnt = end - base; if (ecnt > 8) ecnt = 8;
        for (int j = 0; j < ecnt; ++j) {
            int s = __shfl(sl, j * 8);
            float a = bf2f(actb[(long)s * 64 + lane]);
#pragma unroll
            for (int hh = 0; hh < NH; ++hh)
                acc[hh] += __shfl(al, j * 8 + hh) * a;
        }
    }
    {   // self
        float aself = __expf(selfe - m) * invden;
        float a = bf2f(actb[(long)node * 64 + lane]);
#pragma unroll
        for (int hh = 0; hh < NH; ++hh)
            acc[hh] += __shfl(aself, hh) * a;
    }
#pragma unroll
    for (int hh = 0; hh < NH; ++hh)
        agg[(long)node * 512 + hh * 64 + lane] = __float2bfloat16(acc[hh]);
}

// ---------------- final log_softmax (32 cols) ----------------
__global__ __launch_bounds__(256) void logsoftmax_kernel(const float* __restrict__ acc,
        const float* __restrict__ b, float* __restrict__ out, int n) {
    int idx = blockIdx.x * 256 + threadIdx.x;
    int nd = idx >> 5, lane = idx & 31;
    if (nd >= n) return;
    float v = acc[idx] * 0.125f + b[lane];
    float m = v;
    for (int off = 16; off; off >>= 1) m = fmaxf(m, __shfl_xor(m, off, 32));
    float exv = __expf(v - m);
    float ssum = exv;
    for (int off = 16; off; off >>= 1) ssum += __shfl_xor(ssum, off, 32);
    out[idx] = v - m - logf(ssum);
}

// ---------------- launch ----------------
extern "C" void kernel_launch(void* const* d_in, const int* in_sizes, int n_in,
                              void* d_out, int out_size, void* d_ws, size_t ws_size,
                              hipStream_t stream) {
    const float* x        = (const float*)d_in[0];
    const int*   eidx     = (const int*)d_in[1];
    const float* gcn1_w   = (const float*)d_in[2];
    const float* gcn1_b   = (const float*)d_in[3];
    const float* bn1_g    = (const float*)d_in[4];
    const float* bn1_b    = (const float*)d_in[5];
    const float* bn1_m    = (const float*)d_in[6];
    const float* bn1_v    = (const float*)d_in[7];
    const float* gat1_w   = (const float*)d_in[8];
    const float* gat1_as  = (const float*)d_in[9];
    const float* gat1_ad  = (const float*)d_in[10];
    const float* gat1_b   = (const float*)d_in[11];
    const float* gcn2_w   = (const float*)d_in[12];
    const float* gcn2_b   = (const float*)d_in[13];
    const float* bn2_g    = (const float*)d_in[14];
    const float* bn2_b    = (const float*)d_in[15];
    const float* bn2_m    = (const float*)d_in[16];
    const float* bn2_v    = (const float*)d_in[17];
    const float* gat2_w   = (const float*)d_in[18];
    const float* gat2_as  = (const float*)d_in[19];
    const float* gat2_ad  = (const float*)d_in[20];
    const float* gat2_b   = (const float*)d_in[21];
    float* out = (float*)d_out;

    const int* esrc = eidx;
    const int* edst = eidx + NE;

    // workspace (~84 MB, < proven-safe 110.6 MB)
    float* ws = (float*)d_ws;
    int*   cnt    = (int*)ws;                         // 50048
    int*   rowptr = cnt + 50048;                      // 50048
    int*   cursor = rowptr + 50048;                   // 50048
    int*   csrc   = cursor + 50048;                   // 800000
    float* dinv   = (float*)(csrc + 800000);          // 50048
    float* es     = dinv + 50048;                     // 400000
    float* ed     = es + 400000;                      // 400000
    float* was    = ed + 400000;                      // 512
    float* wad    = was + 512;                        // 512
    float* wprime = wad + 512;                        // 512*64
    float* buf32  = wprime + 512 * 64;                // N*32 f32
    bf16*  actb   = (bf16*)(buf32 + (size_t)NN * 32); // N*64 bf16
    bf16*  mmbf   = actb + (size_t)NN * 64;           // N*64 bf16
    bf16*  agg    = mmbf + (size_t)NN * 64;           // N*512 bf16

    auto cdiv = [](long a, long b) { return (int)((a + b - 1) / b); };
    const int GB = cdiv(NN, 64);       // 782 row-blocks for matmuls
    const int NB = cdiv(NN, 4);        // 12500 node-blocks (wave per node)

    // ---- CSR build ----
    zero_int_kernel<<<cdiv(NN, 256), 256, 0, stream>>>(cnt, NN);
    hist_kernel<<<cdiv(NE, 256), 256, 0, stream>>>(edst, cnt, NE);
    scan_kernel<<<1, 1024, 0, stream>>>(cnt, rowptr, cursor, dinv);
    scatter_kernel<<<cdiv(NE, 256), 256, 0, stream>>>(esrc, edst, cursor, csrc, NE);

    // ---- GCN1 ----
    mm_kernel<IND, false, 1><<<dim3(GB, 1), 256, 0, stream>>>(x, gcn1_w, mmbf, nullptr, NN, 64);
    gcn_fused_kernel<<<NB, 256, 0, stream>>>(rowptr, csrc, dinv, mmbf,
        gcn1_b, bn1_g, bn1_b, bn1_m, bn1_v, actb);

    // ---- GAT1 (C=64): scores from act, aggregate in act-space, then project ----
    proj_aw_kernel<64><<<2, 256, 0, stream>>>(gat1_w, gat1_as, gat1_ad, was, wad);
    scores_kernel<<<cdiv((long)NN * NH, 256), 256, 0, stream>>>(actb, was, wad, es, ed, NN);
    gat_agg_kernel<<<NB, 256, 0, stream>>>(rowptr, csrc, es, ed, actb, agg);
    reshape_w_kernel<64><<<cdiv(512 * 64, 256), 256, 0, stream>>>(gat1_w, wprime);
    mm_kernel<512, true, 2><<<dim3(GB, 1), 256, 0, stream>>>(agg, wprime, actb, gat1_b, NN, 64);

    // ---- GCN2 ----
    mm_kernel<64, true, 1><<<dim3(GB, 1), 256, 0, stream>>>(actb, gcn2_w, mmbf, nullptr, NN, 64);
    gcn_fused_kernel<<<NB, 256, 0, stream>>>(rowptr, csrc, dinv, mmbf,
        gcn2_b, bn2_g, bn2_b, bn2_m, bn2_v, actb);

    // ---- GAT2 (C=32) ----
    proj_aw_kernel<32><<<2, 256, 0, stream>>>(gat2_w, gat2_as, gat2_ad, was, wad);
    scores_kernel<<<cdiv((long)NN * NH, 256), 256, 0, stream>>>(actb, was, wad, es, ed, NN);
    gat_agg_kernel<<<NB, 256, 0, stream>>>(rowptr, csrc, es, ed, actb, agg);
    reshape_w_kernel<32><<<cdiv(512 * 32, 256), 256, 0, stream>>>(gat2_w, wprime);
    mm_kernel<512, true, 0><<<dim3(GB, 1), 256, 0, stream>>>(agg, wprime, buf32, nullptr, NN, 32);

    // ---- log_softmax -> fp32 out ----
    logsoftmax_kernel<<<cdiv((long)NN * 32, 256), 256, 0, stream>>>(buf32, gat2_b, out, NN);
}

// Round 9
// 651.668 us; speedup vs baseline: 1.1969x; 1.1969x over previous
//
#include <hip/hip_runtime.h>
#include <hip/hip_bf16.h>

#define NN 50000
#define NE 800000
#define IND 128
#define NH 8
#define NBLK 196   // cdiv(NN,256)

typedef __hip_bfloat16 bf16;
typedef __attribute__((ext_vector_type(8))) short short8;
typedef __attribute__((ext_vector_type(8))) __bf16 bf16x8;
typedef __attribute__((ext_vector_type(4))) float floatx4;

// float -> bf16 bits, round-to-nearest-even (finite inputs only)
static __device__ __forceinline__ short f2bf_bits(float f) {
    unsigned u = __float_as_uint(f);
    u = (u + 0x7fffu + ((u >> 16) & 1u)) >> 16;
    return (short)u;
}
static __device__ __forceinline__ float bf2f(bf16 v) { return __bfloat162float(v); }

// ---------------- CSR build ----------------
__global__ void zero_int_kernel(int* p, int n) {
    int i = blockIdx.x * 256 + threadIdx.x;
    if (i < n) p[i] = 0;
}
__global__ void hist_kernel(const int* __restrict__ edst, int* __restrict__ cnt, int e) {
    int i = blockIdx.x * 256 + threadIdx.x;
    if (i < e) atomicAdd(&cnt[edst[i]], 1);
}
// hierarchical exclusive scan: (1) per-block local scan, (2) scan of block sums, (3) fixup
__global__ __launch_bounds__(256) void scan1_kernel(const int* __restrict__ cnt,
        int* __restrict__ pre, int* __restrict__ bsum) {
    __shared__ int sh[256];
    const int tid = threadIdx.x;
    const int idx = blockIdx.x * 256 + tid;
    int c = (idx < NN) ? cnt[idx] : 0;
    sh[tid] = c; __syncthreads();
    int val = c;
#pragma unroll
    for (int off = 1; off < 256; off <<= 1) {
        int t = (tid >= off) ? sh[tid - off] : 0;
        __syncthreads();
        val += t; sh[tid] = val;
        __syncthreads();
    }
    if (idx < NN) pre[idx] = val - c;   // exclusive
    if (tid == 255) bsum[blockIdx.x] = val;
}
__global__ __launch_bounds__(256) void scan2_kernel(int* __restrict__ bsum) {
    __shared__ int sh[256];
    const int tid = threadIdx.x;
    int v = (tid < NBLK) ? bsum[tid] : 0;
    sh[tid] = v; __syncthreads();
    int val = v;
#pragma unroll
    for (int off = 1; off < 256; off <<= 1) {
        int t = (tid >= off) ? sh[tid - off] : 0;
        __syncthreads();
        val += t; sh[tid] = val;
        __syncthreads();
    }
    if (tid < NBLK) bsum[tid] = val - v;   // exclusive
}
__global__ __launch_bounds__(256) void scan3_kernel(const int* __restrict__ pre,
        const int* __restrict__ bsum, const int* __restrict__ cnt,
        int* __restrict__ rowptr, int* __restrict__ cursor, float* __restrict__ dinv) {
    const int idx = blockIdx.x * 256 + threadIdx.x;
    if (idx < NN) {
        int r = pre[idx] + bsum[idx >> 8];
        rowptr[idx] = r;
        cursor[idx] = r;
        dinv[idx] = rsqrtf((float)cnt[idx] + 1.f);
    }
    if (idx == 0) rowptr[NN] = NE;
}
__global__ void scatter_kernel(const int* __restrict__ esrc, const int* __restrict__ edst,
        int* __restrict__ cursor, int* __restrict__ csrc, int e) {
    int i = blockIdx.x * 256 + threadIdx.x;
    if (i >= e) return;
    int d = edst[i];
    int pos = atomicAdd(&cursor[d], 1);
    csrc[pos] = esrc[i];
}

// ---------------- MFMA matmul: C[n,M] = A[n,K] @ W[K,M] ----------------
// K-chunked LDS staging (BK=128). W fp32; A fp32 or bf16 (ABF16).
// EPI 0: raw fp32; 1: plain bf16; 2: bf16 relu(v*0.125+bias[col]).
// Fragment layouts verified R6.
template<int K, bool ABF16, int EPI>
__global__ __launch_bounds__(256) void mm_kernel(const void* __restrict__ A,
        const float* __restrict__ W, void* __restrict__ C,
        const float* __restrict__ bias, int nrows, int M) {
    constexpr int BK = (K > 128) ? 128 : K;
    __shared__ __align__(16) short Alds[64][BK + 8];
    __shared__ __align__(16) short Wlds[64][BK + 8];   // transposed: Wlds[m][k]
    const int row0 = blockIdx.x * 64;
    const int m0   = blockIdx.y * 64;
    const int tid  = threadIdx.x;
    const int lane = tid & 63, wave = tid >> 6;
    const int lr = lane & 15, q = lane >> 4;
    const int rw = wave * 16;
    floatx4 acc[4] = {};

    for (int kc = 0; kc < K; kc += BK) {
        if (kc) __syncthreads();
        constexpr int KB = BK / 8;
        for (int i = tid; i < 64 * KB; i += 256) {
            int r = i / KB, kb = i % KB;
            int row = row0 + r;
            short8 v = {0, 0, 0, 0, 0, 0, 0, 0};
            if (row < nrows) {
                if (ABF16) {
                    v = *(const short8*)((const short*)A + (long)row * K + kc + kb * 8);
                } else {
                    const float* ap = (const float*)A + (long)row * K + kc + kb * 8;
                    floatx4 va = *(const floatx4*)ap;
                    floatx4 vb = *(const floatx4*)(ap + 4);
#pragma unroll
                    for (int j = 0; j < 4; ++j) { v[j] = f2bf_bits(va[j]); v[4 + j] = f2bf_bits(vb[j]); }
                }
            }
            *(short8*)&Alds[r][kb * 8] = v;
        }
        for (int i = tid; i < BK * 64; i += 256) {
            int k = i >> 6, m = i & 63;
            Wlds[m][k] = (m0 + m < M) ? f2bf_bits(W[(long)(kc + k) * M + m0 + m]) : (short)0;
        }
        __syncthreads();
#pragma unroll
        for (int k0 = 0; k0 < BK; k0 += 32) {
            bf16x8 a = __builtin_bit_cast(bf16x8, *(const short8*)&Alds[rw + lr][k0 + q * 8]);
#pragma unroll
            for (int c = 0; c < 4; ++c) {
                bf16x8 b = __builtin_bit_cast(bf16x8, *(const short8*)&Wlds[c * 16 + lr][k0 + q * 8]);
                acc[c] = __builtin_amdgcn_mfma_f32_16x16x32_bf16(a, b, acc[c], 0, 0, 0);
            }
        }
    }
#pragma unroll
    for (int c = 0; c < 4; ++c)
#pragma unroll
        for (int r = 0; r < 4; ++r) {
            int row = row0 + rw + q * 4 + r;
            int col = m0 + c * 16 + lr;
            if (row < nrows && col < M) {
                long o = (long)row * M + col;
                float v = acc[c][r];
                if (EPI == 0) ((float*)C)[o] = v;
                else if (EPI == 1) ((bf16*)C)[o] = __float2bfloat16(v);
                else {
                    v = v * 0.125f + bias[col];
                    ((bf16*)C)[o] = __float2bfloat16(fmaxf(v, 0.f));
                }
            }
        }
}

// ---------------- fused GCN aggregate + bias + BN + ReLU (CSR, no atomics) ----------------
__global__ __launch_bounds__(256) void gcn_fused_kernel(const int* __restrict__ rowptr,
        const int* __restrict__ csrc, const float* __restrict__ dinv,
        const bf16* __restrict__ hin, const float* __restrict__ b,
        const float* __restrict__ gamma, const float* __restrict__ beta,
        const float* __restrict__ mean, const float* __restrict__ var,
        bf16* __restrict__ actout) {
    const int node = blockIdx.x * 4 + (threadIdx.x >> 6);
    if (node >= NN) return;
    const int lane = threadIdx.x & 63;
    const int beg = rowptr[node], end = rowptr[node + 1];
    const float di = dinv[node];
    float acc = di * bf2f(hin[(long)node * 64 + lane]);   // self
    int ei = beg;
    for (; ei + 4 <= end; ei += 4) {
        int s0 = csrc[ei], s1 = csrc[ei + 1], s2 = csrc[ei + 2], s3 = csrc[ei + 3];
        float w0 = dinv[s0], w1 = dinv[s1], w2 = dinv[s2], w3 = dinv[s3];
        float h0 = bf2f(hin[(long)s0 * 64 + lane]);
        float h1 = bf2f(hin[(long)s1 * 64 + lane]);
        float h2 = bf2f(hin[(long)s2 * 64 + lane]);
        float h3 = bf2f(hin[(long)s3 * 64 + lane]);
        acc += w0 * h0 + w1 * h1 + w2 * h2 + w3 * h3;
    }
    for (; ei < end; ++ei) {
        int s = csrc[ei];
        acc += dinv[s] * bf2f(hin[(long)s * 64 + lane]);
    }
    float x = acc * di + b[lane];
    x = (x - mean[lane]) * rsqrtf(var[lane] + 1e-5f) * gamma[lane] + beta[lane];
    actout[(long)node * 64 + lane] = __float2bfloat16(fmaxf(x, 0.f));
}

// ---------------- attention prep: project a-vectors through W ----------------
template<int C>
__global__ void proj_aw_kernel(const float* __restrict__ W, const float* __restrict__ as,
        const float* __restrict__ ad, float* __restrict__ was, float* __restrict__ wad) {
    int idx = blockIdx.x * 256 + threadIdx.x;
    if (idx >= 512) return;
    int h = idx >> 6, c = idx & 63;
    const float* wrow = W + (long)c * (NH * C) + h * C;
    float s = 0.f, d = 0.f;
    for (int cc = 0; cc < C; ++cc) {
        float w = wrow[cc];
        s += w * as[h * C + cc];
        d += w * ad[h * C + cc];
    }
    was[idx] = s; wad[idx] = d;
}
// wp[(h*64+c)*C + c'] = W[c][h*C+c']
template<int C>
__global__ void reshape_w_kernel(const float* __restrict__ W, float* __restrict__ wp) {
    int idx = blockIdx.x * 256 + threadIdx.x;
    if (idx >= 512 * C) return;
    int kk = idx / C, cp = idx % C;
    int h = kk >> 6, c = kk & 63;
    wp[idx] = W[(long)c * (NH * C) + h * C + cp];
}
// es[n,h] = <act[n,:], was[h,:]>
__global__ void scores_kernel(const bf16* __restrict__ actb, const float* __restrict__ was,
        const float* __restrict__ wad, float* __restrict__ es, float* __restrict__ ed, int n) {
    int idx = blockIdx.x * 256 + threadIdx.x;
    if (idx >= n * NH) return;
    int nd = idx >> 3, h = idx & 7;
    const bf16* ap = actb + (long)nd * 64;
    float s = 0.f, d = 0.f;
    for (int c = 0; c < 64; ++c) {
        float v = bf2f(ap[c]);
        s += v * was[h * 64 + c];
        d += v * wad[h * 64 + c];
    }
    es[idx] = s; ed[idx] = d;
}

// ---------------- GAT aggregation in act-space (CSR, no atomics) ----------------
__global__ __launch_bounds__(256) void gat_agg_kernel(const int* __restrict__ rowptr,
        const int* __restrict__ csrc, const float* __restrict__ es, const float* __restrict__ ed,
        const bf16* __restrict__ actb, bf16* __restrict__ agg) {
    const int node = blockIdx.x * 4 + (threadIdx.x >> 6);
    if (node >= NN) return;
    const int lane = threadIdx.x & 63;
    const int h = lane & 7, slot = lane >> 3;
    const int beg = rowptr[node], end = rowptr[node + 1];
    const float edr = ed[node * NH + h];

    float selfe = es[node * NH + h] + edr;
    selfe = selfe > 0.f ? selfe : 0.2f * selfe;

    // ---- Phase A: online softmax (m, den) ----
    float m, den;
    if (slot == 0) { m = selfe; den = 1.f; }
    else           { m = -3e38f; den = 0.f; }
    for (int base = beg; base < end; base += 8) {
        int ei = base + slot;
        float e = -3e38f;
        if (ei < end) {
            int s = csrc[ei];
            e = es[s * NH + h] + edr;
            e = e > 0.f ? e : 0.2f * e;
        }
        float mn = fmaxf(m, e);
        den = den * __expf(m - mn) + ((ei < end) ? __expf(e - mn) : 0.f);
        m = mn;
    }
#pragma unroll
    for (int off = 8; off < 64; off <<= 1) {
        float m2 = __shfl_xor(m, off), d2 = __shfl_xor(den, off);
        float mn = fmaxf(m, m2);
        den = den * __expf(m - mn) + d2 * __expf(m2 - mn);
        m = mn;
    }
    const float invden = 1.f / (den + 1e-16f);

    // ---- Phase B ----
    float acc[NH] = {0.f, 0.f, 0.f, 0.f, 0.f, 0.f, 0.f, 0.f};
    for (int base = beg; base < end; base += 8) {
        int ei = base + slot;
        float al = 0.f; int sl = 0;
        if (ei < end) {
            sl = csrc[ei];
            float e = es[sl * NH + h] + edr;
            e = e > 0.f ? e : 0.2f * e;
            al = __expf(e - m) * invden;
        }
        int ecnt = end - base; if (ecnt > 8) ecnt = 8;
        for (int j = 0; j < ecnt; ++j) {
            int s = __shfl(sl, j * 8);
            float a = bf2f(actb[(long)s * 64 + lane]);
#pragma unroll
            for (int hh = 0; hh < NH; ++hh)
                acc[hh] += __shfl(al, j * 8 + hh) * a;
        }
    }
    {   // self
        float aself = __expf(selfe - m) * invden;
        float a = bf2f(actb[(long)node * 64 + lane]);
#pragma unroll
        for (int hh = 0; hh < NH; ++hh)
            acc[hh] += __shfl(aself, hh) * a;
    }
#pragma unroll
    for (int hh = 0; hh < NH; ++hh)
        agg[(long)node * 512 + hh * 64 + lane] = __float2bfloat16(acc[hh]);
}

// ---------------- final log_softmax (32 cols) ----------------
__global__ __launch_bounds__(256) void logsoftmax_kernel(const float* __restrict__ acc,
        const float* __restrict__ b, float* __restrict__ out, int n) {
    int idx = blockIdx.x * 256 + threadIdx.x;
    int nd = idx >> 5, lane = idx & 31;
    if (nd >= n) return;
    float v = acc[idx] * 0.125f + b[lane];
    float m = v;
    for (int off = 16; off; off >>= 1) m = fmaxf(m, __shfl_xor(m, off, 32));
    float exv = __expf(v - m);
    float ssum = exv;
    for (int off = 16; off; off >>= 1) ssum += __shfl_xor(ssum, off, 32);
    out[idx] = v - m - logf(ssum);
}

// ---------------- launch ----------------
extern "C" void kernel_launch(void* const* d_in, const int* in_sizes, int n_in,
                              void* d_out, int out_size, void* d_ws, size_t ws_size,
                              hipStream_t stream) {
    const float* x        = (const float*)d_in[0];
    const int*   eidx     = (const int*)d_in[1];
    const float* gcn1_w   = (const float*)d_in[2];
    const float* gcn1_b   = (const float*)d_in[3];
    const float* bn1_g    = (const float*)d_in[4];
    const float* bn1_b    = (const float*)d_in[5];
    const float* bn1_m    = (const float*)d_in[6];
    const float* bn1_v    = (const float*)d_in[7];
    const float* gat1_w   = (const float*)d_in[8];
    const float* gat1_as  = (const float*)d_in[9];
    const float* gat1_ad  = (const float*)d_in[10];
    const float* gat1_b   = (const float*)d_in[11];
    const float* gcn2_w   = (const float*)d_in[12];
    const float* gcn2_b   = (const float*)d_in[13];
    const float* bn2_g    = (const float*)d_in[14];
    const float* bn2_b    = (const float*)d_in[15];
    const float* bn2_m    = (const float*)d_in[16];
    const float* bn2_v    = (const float*)d_in[17];
    const float* gat2_w   = (const float*)d_in[18];
    const float* gat2_as  = (const float*)d_in[19];
    const float* gat2_ad  = (const float*)d_in[20];
    const float* gat2_b   = (const float*)d_in[21];
    float* out = (float*)d_out;

    const int* esrc = eidx;
    const int* edst = eidx + NE;

    // workspace (~84 MB, < proven-safe 110.6 MB)
    float* ws = (float*)d_ws;
    int*   cnt    = (int*)ws;                         // 50048
    int*   rowptr = cnt + 50048;                      // 50048
    int*   cursor = rowptr + 50048;                   // 50048
    int*   csrc   = cursor + 50048;                   // 800000
    float* dinv   = (float*)(csrc + 800000);          // 50048
    float* es     = dinv + 50048;                     // 400000
    float* ed     = es + 400000;                      // 400000
    float* was    = ed + 400000;                      // 512
    float* wad    = was + 512;                        // 512
    int*   bsum   = (int*)(wad + 512);                // 256
    int*   pre    = bsum + 256;                       // 50048
    float* wprime = (float*)(pre + 50048);            // 512*64
    float* buf32  = wprime + 512 * 64;                // N*32 f32
    bf16*  actb   = (bf16*)(buf32 + (size_t)NN * 32); // N*64 bf16
    bf16*  mmbf   = actb + (size_t)NN * 64;           // N*64 bf16
    bf16*  agg    = mmbf + (size_t)NN * 64;           // N*512 bf16

    auto cdiv = [](long a, long b) { return (int)((a + b - 1) / b); };
    const int GB = cdiv(NN, 64);       // 782 row-blocks for matmuls
    const int NB = cdiv(NN, 4);        // 12500 node-blocks (wave per node)

    // ---- CSR build (hierarchical scan) ----
    zero_int_kernel<<<cdiv(NN, 256), 256, 0, stream>>>(cnt, NN);
    hist_kernel<<<cdiv(NE, 256), 256, 0, stream>>>(edst, cnt, NE);
    scan1_kernel<<<NBLK, 256, 0, stream>>>(cnt, pre, bsum);
    scan2_kernel<<<1, 256, 0, stream>>>(bsum);
    scan3_kernel<<<NBLK, 256, 0, stream>>>(pre, bsum, cnt, rowptr, cursor, dinv);
    scatter_kernel<<<cdiv(NE, 256), 256, 0, stream>>>(esrc, edst, cursor, csrc, NE);

    // ---- GCN1 ----
    mm_kernel<IND, false, 1><<<dim3(GB, 1), 256, 0, stream>>>(x, gcn1_w, mmbf, nullptr, NN, 64);
    gcn_fused_kernel<<<NB, 256, 0, stream>>>(rowptr, csrc, dinv, mmbf,
        gcn1_b, bn1_g, bn1_b, bn1_m, bn1_v, actb);

    // ---- GAT1 (C=64): scores from act, aggregate in act-space, then project ----
    proj_aw_kernel<64><<<2, 256, 0, stream>>>(gat1_w, gat1_as, gat1_ad, was, wad);
    scores_kernel<<<cdiv((long)NN * NH, 256), 256, 0, stream>>>(actb, was, wad, es, ed, NN);
    gat_agg_kernel<<<NB, 256, 0, stream>>>(rowptr, csrc, es, ed, actb, agg);
    reshape_w_kernel<64><<<cdiv(512 * 64, 256), 256, 0, stream>>>(gat1_w, wprime);
    mm_kernel<512, true, 2><<<dim3(GB, 1), 256, 0, stream>>>(agg, wprime, actb, gat1_b, NN, 64);

    // ---- GCN2 ----
    mm_kernel<64, true, 1><<<dim3(GB, 1), 256, 0, stream>>>(actb, gcn2_w, mmbf, nullptr, NN, 64);
    gcn_fused_kernel<<<NB, 256, 0, stream>>>(rowptr, csrc, dinv, mmbf,
        gcn2_b, bn2_g, bn2_b, bn2_m, bn2_v, actb);

    // ---- GAT2 (C=32) ----
    proj_aw_kernel<32><<<2, 256, 0, stream>>>(gat2_w, gat2_as, gat2_ad, was, wad);
    scores_kernel<<<cdiv((long)NN * NH, 256), 256, 0, stream>>>(actb, was, wad, es, ed, NN);
    gat_agg_kernel<<<NB, 256, 0, stream>>>(rowptr, csrc, es, ed, actb, agg);
    reshape_w_kernel<32><<<cdiv(512 * 32, 256), 256, 0, stream>>>(gat2_w, wprime);
    mm_kernel<512, true, 0><<<dim3(GB, 1), 256, 0, stream>>>(agg, wprime, buf32, nullptr, NN, 32);

    // ---- log_softmax -> fp32 out ----
    logsoftmax_kernel<<<cdiv((long)NN * 32, 256), 256, 0, stream>>>(buf32, gat2_b, out, NN);
}

// Round 10
// 619.876 us; speedup vs baseline: 1.2582x; 1.0513x over previous
//
#include <hip/hip_runtime.h>
#include <hip/hip_bf16.h>

#define NN 50000
#define NE 800000
#define IND 128
#define NH 8
#define NBLK 196   // cdiv(NN,256)

typedef __hip_bfloat16 bf16;
typedef __attribute__((ext_vector_type(8))) short short8;
typedef __attribute__((ext_vector_type(8))) __bf16 bf16x8;
typedef __attribute__((ext_vector_type(4))) float floatx4;

// float -> bf16 bits, round-to-nearest-even (finite inputs only)
static __device__ __forceinline__ short f2bf_bits(float f) {
    unsigned u = __float_as_uint(f);
    u = (u + 0x7fffu + ((u >> 16) & 1u)) >> 16;
    return (short)u;
}
static __device__ __forceinline__ float bf2f(bf16 v) { return __bfloat162float(v); }

// ---------------- CSR build ----------------
__global__ void zero_int_kernel(int* p, int n) {
    int i = blockIdx.x * 256 + threadIdx.x;
    if (i < n) p[i] = 0;
}
__global__ void hist_kernel(const int* __restrict__ edst, int* __restrict__ cnt, int e) {
    int i = blockIdx.x * 256 + threadIdx.x;
    if (i < e) atomicAdd(&cnt[edst[i]], 1);
}
// hierarchical exclusive scan: (1) per-block local scan, (2) scan of block sums, (3) fixup
__global__ __launch_bounds__(256) void scan1_kernel(const int* __restrict__ cnt,
        int* __restrict__ pre, int* __restrict__ bsum) {
    __shared__ int sh[256];
    const int tid = threadIdx.x;
    const int idx = blockIdx.x * 256 + tid;
    int c = (idx < NN) ? cnt[idx] : 0;
    sh[tid] = c; __syncthreads();
    int val = c;
#pragma unroll
    for (int off = 1; off < 256; off <<= 1) {
        int t = (tid >= off) ? sh[tid - off] : 0;
        __syncthreads();
        val += t; sh[tid] = val;
        __syncthreads();
    }
    if (idx < NN) pre[idx] = val - c;   // exclusive
    if (tid == 255) bsum[blockIdx.x] = val;
}
__global__ __launch_bounds__(256) void scan2_kernel(int* __restrict__ bsum) {
    __shared__ int sh[256];
    const int tid = threadIdx.x;
    int v = (tid < NBLK) ? bsum[tid] : 0;
    sh[tid] = v; __syncthreads();
    int val = v;
#pragma unroll
    for (int off = 1; off < 256; off <<= 1) {
        int t = (tid >= off) ? sh[tid - off] : 0;
        __syncthreads();
        val += t; sh[tid] = val;
        __syncthreads();
    }
    if (tid < NBLK) bsum[tid] = val - v;   // exclusive
}
__global__ __launch_bounds__(256) void scan3_kernel(const int* __restrict__ pre,
        const int* __restrict__ bsum, const int* __restrict__ cnt,
        int* __restrict__ rowptr, int* __restrict__ cursor, float* __restrict__ dinv) {
    const int idx = blockIdx.x * 256 + threadIdx.x;
    if (idx < NN) {
        int r = pre[idx] + bsum[idx >> 8];
        rowptr[idx] = r;
        cursor[idx] = r;
        dinv[idx] = rsqrtf((float)cnt[idx] + 1.f);
    }
    if (idx == 0) rowptr[NN] = NE;
}
__global__ void scatter_kernel(const int* __restrict__ esrc, const int* __restrict__ edst,
        int* __restrict__ cursor, int* __restrict__ csrc, int e) {
    int i = blockIdx.x * 256 + threadIdx.x;
    if (i >= e) return;
    int d = edst[i];
    int pos = atomicAdd(&cursor[d], 1);
    csrc[pos] = esrc[i];
}

// ---------------- MFMA matmul: C[n,M] = A[n,K] @ W[K,M] ----------------
// K-chunked LDS staging (BK=128). W fp32; A fp32 or bf16 (ABF16).
// EPI 0: raw fp32; 1: plain bf16; 2: bf16 relu(v*0.125+bias[col]).
// Fragment layouts verified R6.
template<int K, bool ABF16, int EPI>
__global__ __launch_bounds__(256) void mm_kernel(const void* __restrict__ A,
        const float* __restrict__ W, void* __restrict__ C,
        const float* __restrict__ bias, int nrows, int M) {
    constexpr int BK = (K > 128) ? 128 : K;
    __shared__ __align__(16) short Alds[64][BK + 8];
    __shared__ __align__(16) short Wlds[64][BK + 8];   // transposed: Wlds[m][k]
    const int row0 = blockIdx.x * 64;
    const int m0   = blockIdx.y * 64;
    const int tid  = threadIdx.x;
    const int lane = tid & 63, wave = tid >> 6;
    const int lr = lane & 15, q = lane >> 4;
    const int rw = wave * 16;
    floatx4 acc[4] = {};

    for (int kc = 0; kc < K; kc += BK) {
        if (kc) __syncthreads();
        constexpr int KB = BK / 8;
        for (int i = tid; i < 64 * KB; i += 256) {
            int r = i / KB, kb = i % KB;
            int row = row0 + r;
            short8 v = {0, 0, 0, 0, 0, 0, 0, 0};
            if (row < nrows) {
                if (ABF16) {
                    v = *(const short8*)((const short*)A + (long)row * K + kc + kb * 8);
                } else {
                    const float* ap = (const float*)A + (long)row * K + kc + kb * 8;
                    floatx4 va = *(const floatx4*)ap;
                    floatx4 vb = *(const floatx4*)(ap + 4);
#pragma unroll
                    for (int j = 0; j < 4; ++j) { v[j] = f2bf_bits(va[j]); v[4 + j] = f2bf_bits(vb[j]); }
                }
            }
            *(short8*)&Alds[r][kb * 8] = v;
        }
        for (int i = tid; i < BK * 64; i += 256) {
            int k = i >> 6, m = i & 63;
            Wlds[m][k] = (m0 + m < M) ? f2bf_bits(W[(long)(kc + k) * M + m0 + m]) : (short)0;
        }
        __syncthreads();
#pragma unroll
        for (int k0 = 0; k0 < BK; k0 += 32) {
            bf16x8 a = __builtin_bit_cast(bf16x8, *(const short8*)&Alds[rw + lr][k0 + q * 8]);
#pragma unroll
            for (int c = 0; c < 4; ++c) {
                bf16x8 b = __builtin_bit_cast(bf16x8, *(const short8*)&Wlds[c * 16 + lr][k0 + q * 8]);
                acc[c] = __builtin_amdgcn_mfma_f32_16x16x32_bf16(a, b, acc[c], 0, 0, 0);
            }
        }
    }
#pragma unroll
    for (int c = 0; c < 4; ++c)
#pragma unroll
        for (int r = 0; r < 4; ++r) {
            int row = row0 + rw + q * 4 + r;
            int col = m0 + c * 16 + lr;
            if (row < nrows && col < M) {
                long o = (long)row * M + col;
                float v = acc[c][r];
                if (EPI == 0) ((float*)C)[o] = v;
                else if (EPI == 1) ((bf16*)C)[o] = __float2bfloat16(v);
                else {
                    v = v * 0.125f + bias[col];
                    ((bf16*)C)[o] = __float2bfloat16(fmaxf(v, 0.f));
                }
            }
        }
}

// ---------------- fused GCN aggregate + bias + BN + ReLU (CSR, no atomics) ----------------
__global__ __launch_bounds__(256) void gcn_fused_kernel(const int* __restrict__ rowptr,
        const int* __restrict__ csrc, const float* __restrict__ dinv,
        const bf16* __restrict__ hin, const float* __restrict__ b,
        const float* __restrict__ gamma, const float* __restrict__ beta,
        const float* __restrict__ mean, const float* __restrict__ var,
        bf16* __restrict__ actout) {
    const int node = blockIdx.x * 4 + (threadIdx.x >> 6);
    if (node >= NN) return;
    const int lane = threadIdx.x & 63;
    const int beg = rowptr[node], end = rowptr[node + 1];
    const float di = dinv[node];
    float acc = di * bf2f(hin[(long)node * 64 + lane]);   // self
    int ei = beg;
    for (; ei + 4 <= end; ei += 4) {
        int s0 = csrc[ei], s1 = csrc[ei + 1], s2 = csrc[ei + 2], s3 = csrc[ei + 3];
        float w0 = dinv[s0], w1 = dinv[s1], w2 = dinv[s2], w3 = dinv[s3];
        float h0 = bf2f(hin[(long)s0 * 64 + lane]);
        float h1 = bf2f(hin[(long)s1 * 64 + lane]);
        float h2 = bf2f(hin[(long)s2 * 64 + lane]);
        float h3 = bf2f(hin[(long)s3 * 64 + lane]);
        acc += w0 * h0 + w1 * h1 + w2 * h2 + w3 * h3;
    }
    for (; ei < end; ++ei) {
        int s = csrc[ei];
        acc += dinv[s] * bf2f(hin[(long)s * 64 + lane]);
    }
    float x = acc * di + b[lane];
    x = (x - mean[lane]) * rsqrtf(var[lane] + 1e-5f) * gamma[lane] + beta[lane];
    actout[(long)node * 64 + lane] = __float2bfloat16(fmaxf(x, 0.f));
}

// ---------------- attention prep: project a-vectors through W ----------------
template<int C>
__global__ void proj_aw_kernel(const float* __restrict__ W, const float* __restrict__ as,
        const float* __restrict__ ad, float* __restrict__ was, float* __restrict__ wad) {
    int idx = blockIdx.x * 256 + threadIdx.x;
    if (idx >= 512) return;
    int h = idx >> 6, c = idx & 63;
    const float* wrow = W + (long)c * (NH * C) + h * C;
    float s = 0.f, d = 0.f;
    for (int cc = 0; cc < C; ++cc) {
        float w = wrow[cc];
        s += w * as[h * C + cc];
        d += w * ad[h * C + cc];
    }
    was[idx] = s; wad[idx] = d;
}
// wp[(h*64+c)*C + c'] = W[c][h*C+c']
template<int C>
__global__ void reshape_w_kernel(const float* __restrict__ W, float* __restrict__ wp) {
    int idx = blockIdx.x * 256 + threadIdx.x;
    if (idx >= 512 * C) return;
    int kk = idx / C, cp = idx % C;
    int h = kk >> 6, c = kk & 63;
    wp[idx] = W[(long)c * (NH * C) + h * C + cp];
}
// es[n,h] = <act[n,:], was[h,:]>
__global__ void scores_kernel(const bf16* __restrict__ actb, const float* __restrict__ was,
        const float* __restrict__ wad, float* __restrict__ es, float* __restrict__ ed, int n) {
    int idx = blockIdx.x * 256 + threadIdx.x;
    if (idx >= n * NH) return;
    int nd = idx >> 3, h = idx & 7;
    const bf16* ap = actb + (long)nd * 64;
    float s = 0.f, d = 0.f;
    for (int c = 0; c < 64; ++c) {
        float v = bf2f(ap[c]);
        s += v * was[h * 64 + c];
        d += v * wad[h * 64 + c];
    }
    es[idx] = s; ed[idx] = d;
}

// ---------------- GAT aggregation in act-space (CSR, no atomics) ----------------
// Phase A: online softmax per head (lanes=(slot,h), butterfly over slots).
// Phase B: alphas + src ids staged in per-wave LDS strip once per 8-edge batch;
// per edge: 1 ds_read_b32 (src, broadcast) + 2 ds_read_b128 (alphas, broadcast) + 8 FMA.
// Replaces 9 shfl(ds_bpermute)/edge -> ~3 LDS ops/edge (R9: LDS-pipe-bound at 101 us).
__global__ __launch_bounds__(256) void gat_agg_kernel(const int* __restrict__ rowptr,
        const int* __restrict__ csrc, const float* __restrict__ es, const float* __restrict__ ed,
        const bf16* __restrict__ actb, bf16* __restrict__ agg) {
    __shared__ __align__(16) float salpha[4][64];
    __shared__ int ssrcs[4][8];
    const int wv = threadIdx.x >> 6;
    const int node = blockIdx.x * 4 + wv;
    if (node >= NN) return;
    const int lane = threadIdx.x & 63;
    const int h = lane & 7, slot = lane >> 3;
    const int beg = rowptr[node], end = rowptr[node + 1];
    const float edr = ed[node * NH + h];

    float selfe = es[node * NH + h] + edr;
    selfe = selfe > 0.f ? selfe : 0.2f * selfe;

    // ---- Phase A: online softmax (m, den) ----
    float m, den;
    if (slot == 0) { m = selfe; den = 1.f; }
    else           { m = -3e38f; den = 0.f; }
    for (int base = beg; base < end; base += 8) {
        int ei = base + slot;
        float e = -3e38f;
        if (ei < end) {
            int s = csrc[ei];
            e = es[s * NH + h] + edr;
            e = e > 0.f ? e : 0.2f * e;
        }
        float mn = fmaxf(m, e);
        den = den * __expf(m - mn) + ((ei < end) ? __expf(e - mn) : 0.f);
        m = mn;
    }
#pragma unroll
    for (int off = 8; off < 64; off <<= 1) {
        float m2 = __shfl_xor(m, off), d2 = __shfl_xor(den, off);
        float mn = fmaxf(m, m2);
        den = den * __expf(m - mn) + d2 * __expf(m2 - mn);
        m = mn;
    }
    const float invden = 1.f / (den + 1e-16f);

    // ---- Phase B: LDS-staged alpha broadcast ----
    float acc[NH] = {0.f, 0.f, 0.f, 0.f, 0.f, 0.f, 0.f, 0.f};
    for (int base = beg; base < end; base += 8) {
        int ei = base + slot;
        float al = 0.f; int sl = 0;
        if (ei < end) {
            sl = csrc[ei];
            float e = es[sl * NH + h] + edr;
            e = e > 0.f ? e : 0.2f * e;
            al = __expf(e - m) * invden;
        }
        salpha[wv][lane] = al;           // lane = slot*8 + h
        if (h == 0) ssrcs[wv][slot] = sl;
        // same-wave LDS write->read: ordered by lgkmcnt (no barrier needed)
        int ecnt = end - base; if (ecnt > 8) ecnt = 8;
        for (int j = 0; j < ecnt; ++j) {
            int s = ssrcs[wv][j];                         // broadcast read
            float a = bf2f(actb[(long)s * 64 + lane]);
            floatx4 al0 = *(const floatx4*)&salpha[wv][j * 8];       // broadcast b128
            floatx4 al1 = *(const floatx4*)&salpha[wv][j * 8 + 4];
            acc[0] += al0[0] * a; acc[1] += al0[1] * a;
            acc[2] += al0[2] * a; acc[3] += al0[3] * a;
            acc[4] += al1[0] * a; acc[5] += al1[1] * a;
            acc[6] += al1[2] * a; acc[7] += al1[3] * a;
        }
    }
    {   // self-loop: stage the 8 self-alphas the same way
        float aself = __expf(selfe - m) * invden;
        if (slot == 0) salpha[wv][h] = aself;
        float a = bf2f(actb[(long)node * 64 + lane]);
        floatx4 al0 = *(const floatx4*)&salpha[wv][0];
        floatx4 al1 = *(const floatx4*)&salpha[wv][4];
        acc[0] += al0[0] * a; acc[1] += al0[1] * a;
        acc[2] += al0[2] * a; acc[3] += al0[3] * a;
        acc[4] += al1[0] * a; acc[5] += al1[1] * a;
        acc[6] += al1[2] * a; acc[7] += al1[3] * a;
    }
#pragma unroll
    for (int hh = 0; hh < NH; ++hh)
        agg[(long)node * 512 + hh * 64 + lane] = __float2bfloat16(acc[hh]);
}

// ---------------- final log_softmax (32 cols) ----------------
__global__ __launch_bounds__(256) void logsoftmax_kernel(const float* __restrict__ acc,
        const float* __restrict__ b, float* __restrict__ out, int n) {
    int idx = blockIdx.x * 256 + threadIdx.x;
    int nd = idx >> 5, lane = idx & 31;
    if (nd >= n) return;
    float v = acc[idx] * 0.125f + b[lane];
    float m = v;
    for (int off = 16; off; off >>= 1) m = fmaxf(m, __shfl_xor(m, off, 32));
    float exv = __expf(v - m);
    float ssum = exv;
    for (int off = 16; off; off >>= 1) ssum += __shfl_xor(ssum, off, 32);
    out[idx] = v - m - logf(ssum);
}

// ---------------- launch ----------------
extern "C" void kernel_launch(void* const* d_in, const int* in_sizes, int n_in,
                              void* d_out, int out_size, void* d_ws, size_t ws_size,
                              hipStream_t stream) {
    const float* x        = (const float*)d_in[0];
    const int*   eidx     = (const int*)d_in[1];
    const float* gcn1_w   = (const float*)d_in[2];
    const float* gcn1_b   = (const float*)d_in[3];
    const float* bn1_g    = (const float*)d_in[4];
    const float* bn1_b    = (const float*)d_in[5];
    const float* bn1_m    = (const float*)d_in[6];
    const float* bn1_v    = (const float*)d_in[7];
    const float* gat1_w   = (const float*)d_in[8];
    const float* gat1_as  = (const float*)d_in[9];
    const float* gat1_ad  = (const float*)d_in[10];
    const float* gat1_b   = (const float*)d_in[11];
    const float* gcn2_w   = (const float*)d_in[12];
    const float* gcn2_b   = (const float*)d_in[13];
    const float* bn2_g    = (const float*)d_in[14];
    const float* bn2_b    = (const float*)d_in[15];
    const float* bn2_m    = (const float*)d_in[16];
    const float* bn2_v    = (const float*)d_in[17];
    const float* gat2_w   = (const float*)d_in[18];
    const float* gat2_as  = (const float*)d_in[19];
    const float* gat2_ad  = (const float*)d_in[20];
    const float* gat2_b   = (const float*)d_in[21];
    float* out = (float*)d_out;

    const int* esrc = eidx;
    const int* edst = eidx + NE;

    // workspace (~84 MB, < proven-safe 110.6 MB)
    float* ws = (float*)d_ws;
    int*   cnt    = (int*)ws;                         // 50048
    int*   rowptr = cnt + 50048;                      // 50048
    int*   cursor = rowptr + 50048;                   // 50048
    int*   csrc   = cursor + 50048;                   // 800000
    float* dinv   = (float*)(csrc + 800000);          // 50048
    float* es     = dinv + 50048;                     // 400000
    float* ed     = es + 400000;                      // 400000
    float* was    = ed + 400000;                      // 512
    float* wad    = was + 512;                        // 512
    int*   bsum   = (int*)(wad + 512);                // 256
    int*   pre    = bsum + 256;                       // 50048
    float* wprime = (float*)(pre + 50048);            // 512*64
    float* buf32  = wprime + 512 * 64;                // N*32 f32
    bf16*  actb   = (bf16*)(buf32 + (size_t)NN * 32); // N*64 bf16
    bf16*  mmbf   = actb + (size_t)NN * 64;           // N*64 bf16
    bf16*  agg    = mmbf + (size_t)NN * 64;           // N*512 bf16

    auto cdiv = [](long a, long b) { return (int)((a + b - 1) / b); };
    const int GB = cdiv(NN, 64);       // 782 row-blocks for matmuls
    const int NB = cdiv(NN, 4);        // 12500 node-blocks (wave per node)

    // ---- CSR build (hierarchical scan) ----
    zero_int_kernel<<<cdiv(NN, 256), 256, 0, stream>>>(cnt, NN);
    hist_kernel<<<cdiv(NE, 256), 256, 0, stream>>>(edst, cnt, NE);
    scan1_kernel<<<NBLK, 256, 0, stream>>>(cnt, pre, bsum);
    scan2_kernel<<<1, 256, 0, stream>>>(bsum);
    scan3_kernel<<<NBLK, 256, 0, stream>>>(pre, bsum, cnt, rowptr, cursor, dinv);
    scatter_kernel<<<cdiv(NE, 256), 256, 0, stream>>>(esrc, edst, cursor, csrc, NE);

    // ---- GCN1 ----
    mm_kernel<IND, false, 1><<<dim3(GB, 1), 256, 0, stream>>>(x, gcn1_w, mmbf, nullptr, NN, 64);
    gcn_fused_kernel<<<NB, 256, 0, stream>>>(rowptr, csrc, dinv, mmbf,
        gcn1_b, bn1_g, bn1_b, bn1_m, bn1_v, actb);

    // ---- GAT1 (C=64): scores from act, aggregate in act-space, then project ----
    proj_aw_kernel<64><<<2, 256, 0, stream>>>(gat1_w, gat1_as, gat1_ad, was, wad);
    scores_kernel<<<cdiv((long)NN * NH, 256), 256, 0, stream>>>(actb, was, wad, es, ed, NN);
    gat_agg_kernel<<<NB, 256, 0, stream>>>(rowptr, csrc, es, ed, actb, agg);
    reshape_w_kernel<64><<<cdiv(512 * 64, 256), 256, 0, stream>>>(gat1_w, wprime);
    mm_kernel<512, true, 2><<<dim3(GB, 1), 256, 0, stream>>>(agg, wprime, actb, gat1_b, NN, 64);

    // ---- GCN2 ----
    mm_kernel<64, true, 1><<<dim3(GB, 1), 256, 0, stream>>>(actb, gcn2_w, mmbf, nullptr, NN, 64);
    gcn_fused_kernel<<<NB, 256, 0, stream>>>(rowptr, csrc, dinv, mmbf,
        gcn2_b, bn2_g, bn2_b, bn2_m, bn2_v, actb);

    // ---- GAT2 (C=32) ----
    proj_aw_kernel<32><<<2, 256, 0, stream>>>(gat2_w, gat2_as, gat2_ad, was, wad);
    scores_kernel<<<cdiv((long)NN * NH, 256), 256, 0, stream>>>(actb, was, wad, es, ed, NN);
    gat_agg_kernel<<<NB, 256, 0, stream>>>(rowptr, csrc, es, ed, actb, agg);
    reshape_w_kernel<32><<<cdiv(512 * 32, 256), 256, 0, stream>>>(gat2_w, wprime);
    mm_kernel<512, true, 0><<<dim3(GB, 1), 256, 0, stream>>>(agg, wprime, buf32, nullptr, NN, 32);

    // ---- log_softmax -> fp32 out ----
    logsoftmax_kernel<<<cdiv((long)NN * 32, 256), 256, 0, stream>>>(buf32, gat2_b, out, NN);
}

// Round 11
// 570.372 us; speedup vs baseline: 1.3674x; 1.0868x over previous
//
#include <hip/hip_runtime.h>
#include <hip/hip_bf16.h>

#define NN 50000
#define NE 800000
#define IND 128
#define NH 8
#define NBLK 196   // cdiv(NN,256)

typedef __hip_bfloat16 bf16;
typedef __attribute__((ext_vector_type(8))) short short8;
typedef __attribute__((ext_vector_type(8))) __bf16 bf16x8;
typedef __attribute__((ext_vector_type(4))) float floatx4;

// float -> bf16 bits, round-to-nearest-even (finite inputs only)
static __device__ __forceinline__ short f2bf_bits(float f) {
    unsigned u = __float_as_uint(f);
    u = (u + 0x7fffu + ((u >> 16) & 1u)) >> 16;
    return (short)u;
}
static __device__ __forceinline__ float bf2f(bf16 v) { return __bfloat162float(v); }

// ---------------- CSR build ----------------
__global__ void zero_int_kernel(int* p, int n) {
    int i = blockIdx.x * 256 + threadIdx.x;
    if (i < n) p[i] = 0;
}
__global__ void hist_kernel(const int* __restrict__ edst, int* __restrict__ cnt, int e) {
    int i = blockIdx.x * 256 + threadIdx.x;
    if (i < e) atomicAdd(&cnt[edst[i]], 1);
}
__global__ __launch_bounds__(256) void scan1_kernel(const int* __restrict__ cnt,
        int* __restrict__ pre, int* __restrict__ bsum) {
    __shared__ int sh[256];
    const int tid = threadIdx.x;
    const int idx = blockIdx.x * 256 + tid;
    int c = (idx < NN) ? cnt[idx] : 0;
    sh[tid] = c; __syncthreads();
    int val = c;
#pragma unroll
    for (int off = 1; off < 256; off <<= 1) {
        int t = (tid >= off) ? sh[tid - off] : 0;
        __syncthreads();
        val += t; sh[tid] = val;
        __syncthreads();
    }
    if (idx < NN) pre[idx] = val - c;   // exclusive
    if (tid == 255) bsum[blockIdx.x] = val;
}
__global__ __launch_bounds__(256) void scan2_kernel(int* __restrict__ bsum) {
    __shared__ int sh[256];
    const int tid = threadIdx.x;
    int v = (tid < NBLK) ? bsum[tid] : 0;
    sh[tid] = v; __syncthreads();
    int val = v;
#pragma unroll
    for (int off = 1; off < 256; off <<= 1) {
        int t = (tid >= off) ? sh[tid - off] : 0;
        __syncthreads();
        val += t; sh[tid] = val;
        __syncthreads();
    }
    if (tid < NBLK) bsum[tid] = val - v;   // exclusive
}
__global__ __launch_bounds__(256) void scan3_kernel(const int* __restrict__ pre,
        const int* __restrict__ bsum, const int* __restrict__ cnt,
        int* __restrict__ rowptr, int* __restrict__ cursor, float* __restrict__ dinv) {
    const int idx = blockIdx.x * 256 + threadIdx.x;
    if (idx < NN) {
        int r = pre[idx] + bsum[idx >> 8];
        rowptr[idx] = r;
        cursor[idx] = r;
        dinv[idx] = rsqrtf((float)cnt[idx] + 1.f);
    }
    if (idx == 0) rowptr[NN] = NE;
}
__global__ void scatter_kernel(const int* __restrict__ esrc, const int* __restrict__ edst,
        int* __restrict__ cursor, int* __restrict__ csrc, int e) {
    int i = blockIdx.x * 256 + threadIdx.x;
    if (i >= e) return;
    int d = edst[i];
    int pos = atomicAdd(&cursor[d], 1);
    csrc[pos] = esrc[i];
}

// ---------------- MFMA matmul: C[n,M] = A[n,K] @ W[K,M] ----------------
// K-chunked LDS staging (BK=128). W fp32; A fp32 or bf16 (ABF16).
// EPI 0: raw fp32; 1: plain bf16; 2: bf16 relu(v*0.125+bias[col]); 3: bf16 rowscale[row]*v.
template<int K, bool ABF16, int EPI>
__global__ __launch_bounds__(256) void mm_kernel(const void* __restrict__ A,
        const float* __restrict__ W, void* __restrict__ C,
        const float* __restrict__ bias, const float* __restrict__ rowscale,
        int nrows, int M) {
    constexpr int BK = (K > 128) ? 128 : K;
    __shared__ __align__(16) short Alds[64][BK + 8];
    __shared__ __align__(16) short Wlds[64][BK + 8];   // transposed: Wlds[m][k]
    const int row0 = blockIdx.x * 64;
    const int m0   = blockIdx.y * 64;
    const int tid  = threadIdx.x;
    const int lane = tid & 63, wave = tid >> 6;
    const int lr = lane & 15, q = lane >> 4;
    const int rw = wave * 16;
    floatx4 acc[4] = {};

    for (int kc = 0; kc < K; kc += BK) {
        if (kc) __syncthreads();
        constexpr int KB = BK / 8;
        for (int i = tid; i < 64 * KB; i += 256) {
            int r = i / KB, kb = i % KB;
            int row = row0 + r;
            short8 v = {0, 0, 0, 0, 0, 0, 0, 0};
            if (row < nrows) {
                if (ABF16) {
                    v = *(const short8*)((const short*)A + (long)row * K + kc + kb * 8);
                } else {
                    const float* ap = (const float*)A + (long)row * K + kc + kb * 8;
                    floatx4 va = *(const floatx4*)ap;
                    floatx4 vb = *(const floatx4*)(ap + 4);
#pragma unroll
                    for (int j = 0; j < 4; ++j) { v[j] = f2bf_bits(va[j]); v[4 + j] = f2bf_bits(vb[j]); }
                }
            }
            *(short8*)&Alds[r][kb * 8] = v;
        }
        for (int i = tid; i < BK * 64; i += 256) {
            int k = i >> 6, m = i & 63;
            Wlds[m][k] = (m0 + m < M) ? f2bf_bits(W[(long)(kc + k) * M + m0 + m]) : (short)0;
        }
        __syncthreads();
#pragma unroll
        for (int k0 = 0; k0 < BK; k0 += 32) {
            bf16x8 a = __builtin_bit_cast(bf16x8, *(const short8*)&Alds[rw + lr][k0 + q * 8]);
#pragma unroll
            for (int c = 0; c < 4; ++c) {
                bf16x8 b = __builtin_bit_cast(bf16x8, *(const short8*)&Wlds[c * 16 + lr][k0 + q * 8]);
                acc[c] = __builtin_amdgcn_mfma_f32_16x16x32_bf16(a, b, acc[c], 0, 0, 0);
            }
        }
    }
#pragma unroll
    for (int c = 0; c < 4; ++c)
#pragma unroll
        for (int r = 0; r < 4; ++r) {
            int row = row0 + rw + q * 4 + r;
            int col = m0 + c * 16 + lr;
            if (row < nrows && col < M) {
                long o = (long)row * M + col;
                float v = acc[c][r];
                if (EPI == 0) ((float*)C)[o] = v;
                else if (EPI == 1) ((bf16*)C)[o] = __float2bfloat16(v);
                else if (EPI == 2) {
                    v = v * 0.125f + bias[col];
                    ((bf16*)C)[o] = __float2bfloat16(fmaxf(v, 0.f));
                } else {
                    ((bf16*)C)[o] = __float2bfloat16(rowscale[row] * v);
                }
            }
        }
}

// ---------------- fused GCN aggregate + bias + BN + ReLU (CSR, no atomics) ----------------
// hin rows are PREMULTIPLIED by dinv[row] (mm EPI=3) -> per edge: 1 row gather + 1 add.
__global__ __launch_bounds__(256) void gcn_fused_kernel(const int* __restrict__ rowptr,
        const int* __restrict__ csrc, const float* __restrict__ dinv,
        const bf16* __restrict__ hin, const float* __restrict__ b,
        const float* __restrict__ gamma, const float* __restrict__ beta,
        const float* __restrict__ mean, const float* __restrict__ var,
        bf16* __restrict__ actout) {
    const int node = blockIdx.x * 4 + (threadIdx.x >> 6);
    if (node >= NN) return;
    const int lane = threadIdx.x & 63;
    const int beg = rowptr[node], end = rowptr[node + 1];
    const float di = dinv[node];
    float acc = bf2f(hin[(long)node * 64 + lane]);   // self: h' already has di factor
    int ei = beg;
    for (; ei + 4 <= end; ei += 4) {
        int s0 = csrc[ei], s1 = csrc[ei + 1], s2 = csrc[ei + 2], s3 = csrc[ei + 3];
        float h0 = bf2f(hin[(long)s0 * 64 + lane]);
        float h1 = bf2f(hin[(long)s1 * 64 + lane]);
        float h2 = bf2f(hin[(long)s2 * 64 + lane]);
        float h3 = bf2f(hin[(long)s3 * 64 + lane]);
        acc += (h0 + h1) + (h2 + h3);
    }
    for (; ei < end; ++ei) {
        int s = csrc[ei];
        acc += bf2f(hin[(long)s * 64 + lane]);
    }
    float x = acc * di + b[lane];
    x = (x - mean[lane]) * rsqrtf(var[lane] + 1e-5f) * gamma[lane] + beta[lane];
    actout[(long)node * 64 + lane] = __float2bfloat16(fmaxf(x, 0.f));
}

// ---------------- attention prep: project a-vectors through W ----------------
template<int C>
__global__ void proj_aw_kernel(const float* __restrict__ W, const float* __restrict__ as,
        const float* __restrict__ ad, float* __restrict__ was, float* __restrict__ wad) {
    int idx = blockIdx.x * 256 + threadIdx.x;
    if (idx >= 512) return;
    int h = idx >> 6, c = idx & 63;
    const float* wrow = W + (long)c * (NH * C) + h * C;
    float s = 0.f, d = 0.f;
    for (int cc = 0; cc < C; ++cc) {
        float w = wrow[cc];
        s += w * as[h * C + cc];
        d += w * ad[h * C + cc];
    }
    was[idx] = s; wad[idx] = d;
}
// wp[(h*64+c)*C + c'] = W[c][h*C+c']
template<int C>
__global__ void reshape_w_kernel(const float* __restrict__ W, float* __restrict__ wp) {
    int idx = blockIdx.x * 256 + threadIdx.x;
    if (idx >= 512 * C) return;
    int kk = idx / C, cp = idx % C;
    int h = kk >> 6, c = kk & 63;
    wp[idx] = W[(long)c * (NH * C) + h * C + cp];
}
// es[n,h] = <act[n,:], was[h,:]> — wave per node, lanes=(h=lane>>3, cg=lane&7)
__global__ __launch_bounds__(256) void scores_kernel(const bf16* __restrict__ actb,
        const float* __restrict__ was, const float* __restrict__ wad,
        float* __restrict__ es, float* __restrict__ ed, int n) {
    const int node = blockIdx.x * 4 + (threadIdx.x >> 6);
    if (node >= n) return;
    const int lane = threadIdx.x & 63;
    const int h = lane >> 3, cg = lane & 7;
    short8 a8 = *(const short8*)((const short*)actb + (long)node * 64 + cg * 8);
    const float* wsp = was + h * 64 + cg * 8;
    const float* wdp = wad + h * 64 + cg * 8;
    floatx4 ws0 = *(const floatx4*)wsp, ws1 = *(const floatx4*)(wsp + 4);
    floatx4 wd0 = *(const floatx4*)wdp, wd1 = *(const floatx4*)(wdp + 4);
    float s = 0.f, d = 0.f;
#pragma unroll
    for (int j = 0; j < 4; ++j) {
        float v0 = bf2f(__builtin_bit_cast(bf16, a8[j]));
        float v1 = bf2f(__builtin_bit_cast(bf16, a8[4 + j]));
        s += v0 * ws0[j] + v1 * ws1[j];
        d += v0 * wd0[j] + v1 * wd1[j];
    }
#pragma unroll
    for (int off = 1; off < 8; off <<= 1) {
        s += __shfl_xor(s, off);
        d += __shfl_xor(d, off);
    }
    if (cg == 0) { es[node * NH + h] = s; ed[node * NH + h] = d; }
}

// ---------------- GAT aggregation in act-space (CSR, no atomics) ----------------
// Fast path (deg<=64): Phase A caches e/src in registers (unrolled), Phase B computes
// alpha from registers (no loads), stages to per-wave LDS strip, gathers act rows.
// Fallback (deg>64): R10 streaming+recompute path.
__global__ __launch_bounds__(256) void gat_agg_kernel(const int* __restrict__ rowptr,
        const int* __restrict__ csrc, const float* __restrict__ es, const float* __restrict__ ed,
        const bf16* __restrict__ actb, bf16* __restrict__ agg) {
    __shared__ __align__(16) float salpha[4][64];
    __shared__ int ssrcs[4][8];
    const int wv = threadIdx.x >> 6;
    const int node = blockIdx.x * 4 + wv;
    if (node >= NN) return;
    const int lane = threadIdx.x & 63;
    const int h = lane & 7, slot = lane >> 3;
    const int beg = rowptr[node], end = rowptr[node + 1];
    const int deg = end - beg;
    const float edr = ed[node * NH + h];

    float selfe = es[node * NH + h] + edr;
    selfe = selfe > 0.f ? selfe : 0.2f * selfe;

    float m, den;
    if (slot == 0) { m = selfe; den = 1.f; }
    else           { m = -3e38f; den = 0.f; }

    float acc[NH] = {0.f, 0.f, 0.f, 0.f, 0.f, 0.f, 0.f, 0.f};

    if (deg <= 64) {
        // ---- Phase A: register-cached online softmax ----
        float e_r[8]; int s_r[8];
#pragma unroll
        for (int b = 0; b < 8; ++b) {
            e_r[b] = 0.f; s_r[b] = 0;
            int k = b * 8 + slot;
            if (k < deg) {
                int s = csrc[beg + k];
                s_r[b] = s;
                float e = es[s * NH + h] + edr;
                e = e > 0.f ? e : 0.2f * e;
                e_r[b] = e;
                float mn = fmaxf(m, e);
                den = den * __expf(m - mn) + __expf(e - mn);
                m = mn;
            }
        }
#pragma unroll
        for (int off = 8; off < 64; off <<= 1) {
            float m2 = __shfl_xor(m, off), d2 = __shfl_xor(den, off);
            float mn = fmaxf(m, m2);
            den = den * __expf(m - mn) + d2 * __expf(m2 - mn);
            m = mn;
        }
        const float invden = 1.f / (den + 1e-16f);

        // ---- Phase B: alpha from registers, LDS broadcast, gather ----
#pragma unroll
        for (int b = 0; b < 8; ++b) {
            if (b * 8 < deg) {
                int k = b * 8 + slot;
                float al = (k < deg) ? __expf(e_r[b] - m) * invden : 0.f;
                salpha[wv][lane] = al;
                if (h == 0) ssrcs[wv][slot] = s_r[b];
                int ecnt = deg - b * 8; if (ecnt > 8) ecnt = 8;
                for (int j = 0; j < ecnt; ++j) {
                    int s = ssrcs[wv][j];
                    float a = bf2f(actb[(long)s * 64 + lane]);
                    floatx4 al0 = *(const floatx4*)&salpha[wv][j * 8];
                    floatx4 al1 = *(const floatx4*)&salpha[wv][j * 8 + 4];
                    acc[0] += al0[0] * a; acc[1] += al0[1] * a;
                    acc[2] += al0[2] * a; acc[3] += al0[3] * a;
                    acc[4] += al1[0] * a; acc[5] += al1[1] * a;
                    acc[6] += al1[2] * a; acc[7] += al1[3] * a;
                }
            }
        }
    } else {
        // ---- fallback: streaming online softmax + recompute (rare) ----
        for (int base = beg; base < end; base += 8) {
            int ei = base + slot;
            float e = -3e38f;
            if (ei < end) {
                int s = csrc[ei];
                e = es[s * NH + h] + edr;
                e = e > 0.f ? e : 0.2f * e;
            }
            float mn = fmaxf(m, e);
            den = den * __expf(m - mn) + ((ei < end) ? __expf(e - mn) : 0.f);
            m = mn;
        }
#pragma unroll
        for (int off = 8; off < 64; off <<= 1) {
            float m2 = __shfl_xor(m, off), d2 = __shfl_xor(den, off);
            float mn = fmaxf(m, m2);
            den = den * __expf(m - mn) + d2 * __expf(m2 - mn);
            m = mn;
        }
        const float invden = 1.f / (den + 1e-16f);
        for (int base = beg; base < end; base += 8) {
            int ei = base + slot;
            float al = 0.f; int sl = 0;
            if (ei < end) {
                sl = csrc[ei];
                float e = es[sl * NH + h] + edr;
                e = e > 0.f ? e : 0.2f * e;
                al = __expf(e - m) * invden;
            }
            salpha[wv][lane] = al;
            if (h == 0) ssrcs[wv][slot] = sl;
            int ecnt = end - base; if (ecnt > 8) ecnt = 8;
            for (int j = 0; j < ecnt; ++j) {
                int s = ssrcs[wv][j];
                float a = bf2f(actb[(long)s * 64 + lane]);
                floatx4 al0 = *(const floatx4*)&salpha[wv][j * 8];
                floatx4 al1 = *(const floatx4*)&salpha[wv][j * 8 + 4];
                acc[0] += al0[0] * a; acc[1] += al0[1] * a;
                acc[2] += al0[2] * a; acc[3] += al0[3] * a;
                acc[4] += al1[0] * a; acc[5] += al1[1] * a;
                acc[6] += al1[2] * a; acc[7] += al1[3] * a;
            }
        }
    }
    // compute m/den butterfly result is wave-uniform; self-loop term:
    {
        float mfin = m;   // m already combined in both paths
        float aself = __expf(selfe - mfin) / (den + 1e-16f);
        if (slot == 0) salpha[wv][h] = aself;
        float a = bf2f(actb[(long)node * 64 + lane]);
        floatx4 al0 = *(const floatx4*)&salpha[wv][0];
        floatx4 al1 = *(const floatx4*)&salpha[wv][4];
        acc[0] += al0[0] * a; acc[1] += al0[1] * a;
        acc[2] += al0[2] * a; acc[3] += al0[3] * a;
        acc[4] += al1[0] * a; acc[5] += al1[1] * a;
        acc[6] += al1[2] * a; acc[7] += al1[3] * a;
    }
#pragma unroll
    for (int hh = 0; hh < NH; ++hh)
        agg[(long)node * 512 + hh * 64 + lane] = __float2bfloat16(acc[hh]);
}

// ---------------- final log_softmax (32 cols) ----------------
__global__ __launch_bounds__(256) void logsoftmax_kernel(const float* __restrict__ acc,
        const float* __restrict__ b, float* __restrict__ out, int n) {
    int idx = blockIdx.x * 256 + threadIdx.x;
    int nd = idx >> 5, lane = idx & 31;
    if (nd >= n) return;
    float v = acc[idx] * 0.125f + b[lane];
    float m = v;
    for (int off = 16; off; off >>= 1) m = fmaxf(m, __shfl_xor(m, off, 32));
    float exv = __expf(v - m);
    float ssum = exv;
    for (int off = 16; off; off >>= 1) ssum += __shfl_xor(ssum, off, 32);
    out[idx] = v - m - logf(ssum);
}

// ---------------- launch ----------------
extern "C" void kernel_launch(void* const* d_in, const int* in_sizes, int n_in,
                              void* d_out, int out_size, void* d_ws, size_t ws_size,
                              hipStream_t stream) {
    const float* x        = (const float*)d_in[0];
    const int*   eidx     = (const int*)d_in[1];
    const float* gcn1_w   = (const float*)d_in[2];
    const float* gcn1_b   = (const float*)d_in[3];
    const float* bn1_g    = (const float*)d_in[4];
    const float* bn1_b    = (const float*)d_in[5];
    const float* bn1_m    = (const float*)d_in[6];
    const float* bn1_v    = (const float*)d_in[7];
    const float* gat1_w   = (const float*)d_in[8];
    const float* gat1_as  = (const float*)d_in[9];
    const float* gat1_ad  = (const float*)d_in[10];
    const float* gat1_b   = (const float*)d_in[11];
    const float* gcn2_w   = (const float*)d_in[12];
    const float* gcn2_b   = (const float*)d_in[13];
    const float* bn2_g    = (const float*)d_in[14];
    const float* bn2_b    = (const float*)d_in[15];
    const float* bn2_m    = (const float*)d_in[16];
    const float* bn2_v    = (const float*)d_in[17];
    const float* gat2_w   = (const float*)d_in[18];
    const float* gat2_as  = (const float*)d_in[19];
    const float* gat2_ad  = (const float*)d_in[20];
    const float* gat2_b   = (const float*)d_in[21];
    float* out = (float*)d_out;

    const int* esrc = eidx;
    const int* edst = eidx + NE;

    // workspace (~84 MB, < proven-safe 110.6 MB)
    float* ws = (float*)d_ws;
    int*   cnt    = (int*)ws;                         // 50048
    int*   rowptr = cnt + 50048;                      // 50048
    int*   cursor = rowptr + 50048;                   // 50048
    int*   csrc   = cursor + 50048;                   // 800000
    float* dinv   = (float*)(csrc + 800000);          // 50048
    float* es     = dinv + 50048;                     // 400000
    float* ed     = es + 400000;                      // 400000
    float* was    = ed + 400000;                      // 512
    float* wad    = was + 512;                        // 512
    int*   bsum   = (int*)(wad + 512);                // 256
    int*   pre    = bsum + 256;                       // 50048
    float* wprime = (float*)(pre + 50048);            // 512*64
    float* buf32  = wprime + 512 * 64;                // N*32 f32
    bf16*  actb   = (bf16*)(buf32 + (size_t)NN * 32); // N*64 bf16
    bf16*  mmbf   = actb + (size_t)NN * 64;           // N*64 bf16
    bf16*  agg    = mmbf + (size_t)NN * 64;           // N*512 bf16

    auto cdiv = [](long a, long b) { return (int)((a + b - 1) / b); };
    const int GB = cdiv(NN, 64);       // 782 row-blocks for matmuls
    const int NB = cdiv(NN, 4);        // 12500 node-blocks (wave per node)

    // ---- CSR build (hierarchical scan) ----
    zero_int_kernel<<<cdiv(NN, 256), 256, 0, stream>>>(cnt, NN);
    hist_kernel<<<cdiv(NE, 256), 256, 0, stream>>>(edst, cnt, NE);
    scan1_kernel<<<NBLK, 256, 0, stream>>>(cnt, pre, bsum);
    scan2_kernel<<<1, 256, 0, stream>>>(bsum);
    scan3_kernel<<<NBLK, 256, 0, stream>>>(pre, bsum, cnt, rowptr, cursor, dinv);
    scatter_kernel<<<cdiv(NE, 256), 256, 0, stream>>>(esrc, edst, cursor, csrc, NE);

    // ---- GCN1 ----
    mm_kernel<IND, false, 3><<<dim3(GB, 1), 256, 0, stream>>>(x, gcn1_w, mmbf, nullptr, dinv, NN, 64);
    gcn_fused_kernel<<<NB, 256, 0, stream>>>(rowptr, csrc, dinv, mmbf,
        gcn1_b, bn1_g, bn1_b, bn1_m, bn1_v, actb);

    // ---- GAT1 (C=64): scores from act, aggregate in act-space, then project ----
    proj_aw_kernel<64><<<2, 256, 0, stream>>>(gat1_w, gat1_as, gat1_ad, was, wad);
    scores_kernel<<<NB, 256, 0, stream>>>(actb, was, wad, es, ed, NN);
    gat_agg_kernel<<<NB, 256, 0, stream>>>(rowptr, csrc, es, ed, actb, agg);
    reshape_w_kernel<64><<<cdiv(512 * 64, 256), 256, 0, stream>>>(gat1_w, wprime);
    mm_kernel<512, true, 2><<<dim3(GB, 1), 256, 0, stream>>>(agg, wprime, actb, gat1_b, nullptr, NN, 64);

    // ---- GCN2 ----
    mm_kernel<64, true, 3><<<dim3(GB, 1), 256, 0, stream>>>(actb, gcn2_w, mmbf, nullptr, dinv, NN, 64);
    gcn_fused_kernel<<<NB, 256, 0, stream>>>(rowptr, csrc, dinv, mmbf,
        gcn2_b, bn2_g, bn2_b, bn2_m, bn2_v, actb);

    // ---- GAT2 (C=32) ----
    proj_aw_kernel<32><<<2, 256, 0, stream>>>(gat2_w, gat2_as, gat2_ad, was, wad);
    scores_kernel<<<NB, 256, 0, stream>>>(actb, was, wad, es, ed, NN);
    gat_agg_kernel<<<NB, 256, 0, stream>>>(rowptr, csrc, es, ed, actb, agg);
    reshape_w_kernel<32><<<cdiv(512 * 32, 256), 256, 0, stream>>>(gat2_w, wprime);
    mm_kernel<512, true, 0><<<dim3(GB, 1), 256, 0, stream>>>(agg, wprime, buf32, nullptr, nullptr, NN, 32);

    // ---- log_softmax -> fp32 out ----
    logsoftmax_kernel<<<cdiv((long)NN * 32, 256), 256, 0, stream>>>(buf32, gat2_b, out, NN);
}

// Round 12
// 508.856 us; speedup vs baseline: 1.5328x; 1.1209x over previous
//
#include <hip/hip_runtime.h>
#include <hip/hip_bf16.h>

#define NN 50000
#define NE 800000
#define IND 128
#define NH 8
#define NBLK 196   // cdiv(NN,256)

typedef __hip_bfloat16 bf16;
typedef __attribute__((ext_vector_type(8))) short short8;
typedef __attribute__((ext_vector_type(8))) __bf16 bf16x8;
typedef __attribute__((ext_vector_type(4))) float floatx4;

// float -> bf16 bits, round-to-nearest-even (finite inputs only)
static __device__ __forceinline__ short f2bf_bits(float f) {
    unsigned u = __float_as_uint(f);
    u = (u + 0x7fffu + ((u >> 16) & 1u)) >> 16;
    return (short)u;
}
static __device__ __forceinline__ float bf2f(bf16 v) { return __bfloat162float(v); }

// ---------------- CSR build ----------------
__global__ void zero_int_kernel(int* p, int n) {
    int i = blockIdx.x * 256 + threadIdx.x;
    if (i < n) p[i] = 0;
}
__global__ void hist_kernel(const int* __restrict__ edst, int* __restrict__ cnt, int e) {
    int i = blockIdx.x * 256 + threadIdx.x;
    if (i < e) atomicAdd(&cnt[edst[i]], 1);
}
__global__ __launch_bounds__(256) void scan1_kernel(const int* __restrict__ cnt,
        int* __restrict__ pre, int* __restrict__ bsum) {
    __shared__ int sh[256];
    const int tid = threadIdx.x;
    const int idx = blockIdx.x * 256 + tid;
    int c = (idx < NN) ? cnt[idx] : 0;
    sh[tid] = c; __syncthreads();
    int val = c;
#pragma unroll
    for (int off = 1; off < 256; off <<= 1) {
        int t = (tid >= off) ? sh[tid - off] : 0;
        __syncthreads();
        val += t; sh[tid] = val;
        __syncthreads();
    }
    if (idx < NN) pre[idx] = val - c;   // exclusive
    if (tid == 255) bsum[blockIdx.x] = val;
}
__global__ __launch_bounds__(256) void scan2_kernel(int* __restrict__ bsum) {
    __shared__ int sh[256];
    const int tid = threadIdx.x;
    int v = (tid < NBLK) ? bsum[tid] : 0;
    sh[tid] = v; __syncthreads();
    int val = v;
#pragma unroll
    for (int off = 1; off < 256; off <<= 1) {
        int t = (tid >= off) ? sh[tid - off] : 0;
        __syncthreads();
        val += t; sh[tid] = val;
        __syncthreads();
    }
    if (tid < NBLK) bsum[tid] = val - v;   // exclusive
}
__global__ __launch_bounds__(256) void scan3_kernel(const int* __restrict__ pre,
        const int* __restrict__ bsum, const int* __restrict__ cnt,
        int* __restrict__ rowptr, int* __restrict__ cursor, float* __restrict__ dinv) {
    const int idx = blockIdx.x * 256 + threadIdx.x;
    if (idx < NN) {
        int r = pre[idx] + bsum[idx >> 8];
        rowptr[idx] = r;
        cursor[idx] = r;
        dinv[idx] = rsqrtf((float)cnt[idx] + 1.f);
    }
    if (idx == 0) rowptr[NN] = NE;
}
__global__ void scatter_kernel(const int* __restrict__ esrc, const int* __restrict__ edst,
        int* __restrict__ cursor, int* __restrict__ csrc, int e) {
    int i = blockIdx.x * 256 + threadIdx.x;
    if (i >= e) return;
    int d = edst[i];
    int pos = atomicAdd(&cursor[d], 1);
    csrc[pos] = esrc[i];
}

// ---------------- MFMA matmul: C[n,M] = A[n,K] @ W[K,M] ----------------
// K-chunked LDS staging (BK=128). W fp32; A fp32 or bf16 (ABF16).
// EPI 0: raw fp32; 1: plain bf16; 2: bf16 relu(v*0.125+bias[col]); 3: bf16 rowscale[row]*v.
template<int K, bool ABF16, int EPI>
__global__ __launch_bounds__(256) void mm_kernel(const void* __restrict__ A,
        const float* __restrict__ W, void* __restrict__ C,
        const float* __restrict__ bias, const float* __restrict__ rowscale,
        int nrows, int M) {
    constexpr int BK = (K > 128) ? 128 : K;
    __shared__ __align__(16) short Alds[64][BK + 8];
    __shared__ __align__(16) short Wlds[64][BK + 8];   // transposed: Wlds[m][k]
    const int row0 = blockIdx.x * 64;
    const int m0   = blockIdx.y * 64;
    const int tid  = threadIdx.x;
    const int lane = tid & 63, wave = tid >> 6;
    const int lr = lane & 15, q = lane >> 4;
    const int rw = wave * 16;
    floatx4 acc[4] = {};

    for (int kc = 0; kc < K; kc += BK) {
        if (kc) __syncthreads();
        constexpr int KB = BK / 8;
        for (int i = tid; i < 64 * KB; i += 256) {
            int r = i / KB, kb = i % KB;
            int row = row0 + r;
            short8 v = {0, 0, 0, 0, 0, 0, 0, 0};
            if (row < nrows) {
                if (ABF16) {
                    v = *(const short8*)((const short*)A + (long)row * K + kc + kb * 8);
                } else {
                    const float* ap = (const float*)A + (long)row * K + kc + kb * 8;
                    floatx4 va = *(const floatx4*)ap;
                    floatx4 vb = *(const floatx4*)(ap + 4);
#pragma unroll
                    for (int j = 0; j < 4; ++j) { v[j] = f2bf_bits(va[j]); v[4 + j] = f2bf_bits(vb[j]); }
                }
            }
            *(short8*)&Alds[r][kb * 8] = v;
        }
        for (int i = tid; i < BK * 64; i += 256) {
            int k = i >> 6, m = i & 63;
            Wlds[m][k] = (m0 + m < M) ? f2bf_bits(W[(long)(kc + k) * M + m0 + m]) : (short)0;
        }
        __syncthreads();
#pragma unroll
        for (int k0 = 0; k0 < BK; k0 += 32) {
            bf16x8 a = __builtin_bit_cast(bf16x8, *(const short8*)&Alds[rw + lr][k0 + q * 8]);
#pragma unroll
            for (int c = 0; c < 4; ++c) {
                bf16x8 b = __builtin_bit_cast(bf16x8, *(const short8*)&Wlds[c * 16 + lr][k0 + q * 8]);
                acc[c] = __builtin_amdgcn_mfma_f32_16x16x32_bf16(a, b, acc[c], 0, 0, 0);
            }
        }
    }
#pragma unroll
    for (int c = 0; c < 4; ++c)
#pragma unroll
        for (int r = 0; r < 4; ++r) {
            int row = row0 + rw + q * 4 + r;
            int col = m0 + c * 16 + lr;
            if (row < nrows && col < M) {
                long o = (long)row * M + col;
                float v = acc[c][r];
                if (EPI == 0) ((float*)C)[o] = v;
                else if (EPI == 1) ((bf16*)C)[o] = __float2bfloat16(v);
                else if (EPI == 2) {
                    v = v * 0.125f + bias[col];
                    ((bf16*)C)[o] = __float2bfloat16(fmaxf(v, 0.f));
                } else {
                    ((bf16*)C)[o] = __float2bfloat16(rowscale[row] * v);
                }
            }
        }
}

// ---------------- fused GCN aggregate + bias + BN + ReLU (CSR, no atomics) ----------------
// hin rows are PREMULTIPLIED by dinv[row] (mm EPI=3) -> per edge: 1 row gather + 1 add.
__global__ __launch_bounds__(256) void gcn_fused_kernel(const int* __restrict__ rowptr,
        const int* __restrict__ csrc, const float* __restrict__ dinv,
        const bf16* __restrict__ hin, const float* __restrict__ b,
        const float* __restrict__ gamma, const float* __restrict__ beta,
        const float* __restrict__ mean, const float* __restrict__ var,
        bf16* __restrict__ actout) {
    const int node = blockIdx.x * 4 + (threadIdx.x >> 6);
    if (node >= NN) return;
    const int lane = threadIdx.x & 63;
    const int beg = rowptr[node], end = rowptr[node + 1];
    const float di = dinv[node];
    float acc = bf2f(hin[(long)node * 64 + lane]);   // self: h' already has di factor
    int ei = beg;
    for (; ei + 4 <= end; ei += 4) {
        int s0 = csrc[ei], s1 = csrc[ei + 1], s2 = csrc[ei + 2], s3 = csrc[ei + 3];
        float h0 = bf2f(hin[(long)s0 * 64 + lane]);
        float h1 = bf2f(hin[(long)s1 * 64 + lane]);
        float h2 = bf2f(hin[(long)s2 * 64 + lane]);
        float h3 = bf2f(hin[(long)s3 * 64 + lane]);
        acc += (h0 + h1) + (h2 + h3);
    }
    for (; ei < end; ++ei) {
        int s = csrc[ei];
        acc += bf2f(hin[(long)s * 64 + lane]);
    }
    float x = acc * di + b[lane];
    x = (x - mean[lane]) * rsqrtf(var[lane] + 1e-5f) * gamma[lane] + beta[lane];
    actout[(long)node * 64 + lane] = __float2bfloat16(fmaxf(x, 0.f));
}

// ---------------- attention prep: project a-vectors through W ----------------
template<int C>
__global__ void proj_aw_kernel(const float* __restrict__ W, const float* __restrict__ as,
        const float* __restrict__ ad, float* __restrict__ was, float* __restrict__ wad) {
    int idx = blockIdx.x * 256 + threadIdx.x;
    if (idx >= 512) return;
    int h = idx >> 6, c = idx & 63;
    const float* wrow = W + (long)c * (NH * C) + h * C;
    float s = 0.f, d = 0.f;
    for (int cc = 0; cc < C; ++cc) {
        float w = wrow[cc];
        s += w * as[h * C + cc];
        d += w * ad[h * C + cc];
    }
    was[idx] = s; wad[idx] = d;
}
// wp[(h*64+c)*C + c'] = W[c][h*C+c']
template<int C>
__global__ void reshape_w_kernel(const float* __restrict__ W, float* __restrict__ wp) {
    int idx = blockIdx.x * 256 + threadIdx.x;
    if (idx >= 512 * C) return;
    int kk = idx / C, cp = idx % C;
    int h = kk >> 6, c = kk & 63;
    wp[idx] = W[(long)c * (NH * C) + h * C + cp];
}
// es[n,h] = <act[n,:], was[h,:]> — wave per node, lanes=(h=lane>>3, cg=lane&7)
__global__ __launch_bounds__(256) void scores_kernel(const bf16* __restrict__ actb,
        const float* __restrict__ was, const float* __restrict__ wad,
        float* __restrict__ es, float* __restrict__ ed, int n) {
    const int node = blockIdx.x * 4 + (threadIdx.x >> 6);
    if (node >= n) return;
    const int lane = threadIdx.x & 63;
    const int h = lane >> 3, cg = lane & 7;
    short8 a8 = *(const short8*)((const short*)actb + (long)node * 64 + cg * 8);
    const float* wsp = was + h * 64 + cg * 8;
    const float* wdp = wad + h * 64 + cg * 8;
    floatx4 ws0 = *(const floatx4*)wsp, ws1 = *(const floatx4*)(wsp + 4);
    floatx4 wd0 = *(const floatx4*)wdp, wd1 = *(const floatx4*)(wdp + 4);
    float s = 0.f, d = 0.f;
#pragma unroll
    for (int j = 0; j < 4; ++j) {
        float v0 = bf2f(__builtin_bit_cast(bf16, a8[j]));
        float v1 = bf2f(__builtin_bit_cast(bf16, a8[4 + j]));
        s += v0 * ws0[j] + v1 * ws1[j];
        d += v0 * wd0[j] + v1 * wd1[j];
    }
#pragma unroll
    for (int off = 1; off < 8; off <<= 1) {
        s += __shfl_xor(s, off);
        d += __shfl_xor(d, off);
    }
    if (cg == 0) { es[node * NH + h] = s; ed[node * NH + h] = d; }
}

// ---------------- GAT aggregation in act-space (CSR, no atomics) ----------------
// Softmax shifted by the SELF logit (exact: alpha_j = exp(e_j-selfe)/(sum+1)) — removes
// the online-max serial chain and all Phase-B exps. Fast path (deg<=64): exps cached in
// registers, ALL alphas+srcs staged to LDS once, single fully-independent gather loop.
__global__ __launch_bounds__(256) void gat_agg_kernel(const int* __restrict__ rowptr,
        const int* __restrict__ csrc, const float* __restrict__ es, const float* __restrict__ ed,
        const bf16* __restrict__ actb, bf16* __restrict__ agg) {
    __shared__ __align__(16) float salpha[4][512];
    __shared__ int ssrcs[4][64];
    __shared__ __align__(16) float sself[4][8];
    const int wv = threadIdx.x >> 6;
    const int node = blockIdx.x * 4 + wv;
    if (node >= NN) return;
    const int lane = threadIdx.x & 63;
    const int h = lane & 7, slot = lane >> 3;
    const int beg = rowptr[node], end = rowptr[node + 1];
    const int deg = end - beg;
    const float edr = ed[node * NH + h];

    float selfe = es[node * NH + h] + edr;
    selfe = selfe > 0.f ? selfe : 0.2f * selfe;

    float acc[NH] = {0.f, 0.f, 0.f, 0.f, 0.f, 0.f, 0.f, 0.f};

    if (deg <= 64) {
        // ---- Phase A: independent exps, register-cached ----
        float ex_r[8]; int s_r[8];
        float den = 0.f;
#pragma unroll
        for (int b = 0; b < 8; ++b) {
            ex_r[b] = 0.f; s_r[b] = 0;
            int k = b * 8 + slot;
            if (k < deg) {
                int s = csrc[beg + k];
                s_r[b] = s;
                float e = es[s * NH + h] + edr;
                e = e > 0.f ? e : 0.2f * e;
                ex_r[b] = __expf(e - selfe);
                den += ex_r[b];
            }
        }
        den += __shfl_xor(den, 8);
        den += __shfl_xor(den, 16);
        den += __shfl_xor(den, 32);
        const float invden = 1.f / (den + 1.f);   // +1 = self term

        // ---- stage ALL alphas + srcs once ----
#pragma unroll
        for (int b = 0; b < 8; ++b)
            salpha[wv][b * 64 + lane] = ex_r[b] * invden;
        if (h == 0) {
#pragma unroll
            for (int b = 0; b < 8; ++b)
                ssrcs[wv][b * 8 + slot] = s_r[b];
        }
        if (slot == 0) sself[wv][h] = invden;

        // ---- Phase B: single independent gather loop ----
#pragma unroll 4
        for (int k = 0; k < deg; ++k) {
            int s = ssrcs[wv][k];
            float a = bf2f(actb[(long)s * 64 + lane]);
            const float* ap = &salpha[wv][(k >> 3) * 64 + (k & 7) * 8];
            floatx4 al0 = *(const floatx4*)ap;
            floatx4 al1 = *(const floatx4*)(ap + 4);
            acc[0] += al0[0] * a; acc[1] += al0[1] * a;
            acc[2] += al0[2] * a; acc[3] += al0[3] * a;
            acc[4] += al1[0] * a; acc[5] += al1[1] * a;
            acc[6] += al1[2] * a; acc[7] += al1[3] * a;
        }
        {   // self
            float a = bf2f(actb[(long)node * 64 + lane]);
            floatx4 s0 = *(const floatx4*)&sself[wv][0];
            floatx4 s1 = *(const floatx4*)&sself[wv][4];
            acc[0] += s0[0] * a; acc[1] += s0[1] * a;
            acc[2] += s0[2] * a; acc[3] += s0[3] * a;
            acc[4] += s1[0] * a; acc[5] += s1[1] * a;
            acc[6] += s1[2] * a; acc[7] += s1[3] * a;
        }
    } else {
        // ---- fallback (deg>64, rare): streaming two-pass with self-shift ----
        float den = 0.f;
        for (int base = beg; base < end; base += 8) {
            int ei = base + slot;
            if (ei < end) {
                int s = csrc[ei];
                float e = es[s * NH + h] + edr;
                e = e > 0.f ? e : 0.2f * e;
                den += __expf(e - selfe);
            }
        }
        den += __shfl_xor(den, 8);
        den += __shfl_xor(den, 16);
        den += __shfl_xor(den, 32);
        const float invden = 1.f / (den + 1.f);
        for (int base = beg; base < end; base += 8) {
            int ei = base + slot;
            float al = 0.f; int sl = 0;
            if (ei < end) {
                sl = csrc[ei];
                float e = es[sl * NH + h] + edr;
                e = e > 0.f ? e : 0.2f * e;
                al = __expf(e - selfe) * invden;
            }
            salpha[wv][lane] = al;
            if (h == 0) ssrcs[wv][slot] = sl;
            int ecnt = end - base; if (ecnt > 8) ecnt = 8;
            for (int j = 0; j < ecnt; ++j) {
                int s = ssrcs[wv][j];
                float a = bf2f(actb[(long)s * 64 + lane]);
                floatx4 al0 = *(const floatx4*)&salpha[wv][j * 8];
                floatx4 al1 = *(const floatx4*)&salpha[wv][j * 8 + 4];
                acc[0] += al0[0] * a; acc[1] += al0[1] * a;
                acc[2] += al0[2] * a; acc[3] += al0[3] * a;
                acc[4] += al1[0] * a; acc[5] += al1[1] * a;
                acc[6] += al1[2] * a; acc[7] += al1[3] * a;
            }
        }
        {   // self
            if (slot == 0) sself[wv][h] = invden;
            float a = bf2f(actb[(long)node * 64 + lane]);
            floatx4 s0 = *(const floatx4*)&sself[wv][0];
            floatx4 s1 = *(const floatx4*)&sself[wv][4];
            acc[0] += s0[0] * a; acc[1] += s0[1] * a;
            acc[2] += s0[2] * a; acc[3] += s0[3] * a;
            acc[4] += s1[0] * a; acc[5] += s1[1] * a;
            acc[6] += s1[2] * a; acc[7] += s1[3] * a;
        }
    }
#pragma unroll
    for (int hh = 0; hh < NH; ++hh)
        agg[(long)node * 512 + hh * 64 + lane] = __float2bfloat16(acc[hh]);
}

// ---------------- final log_softmax (32 cols) ----------------
__global__ __launch_bounds__(256) void logsoftmax_kernel(const float* __restrict__ acc,
        const float* __restrict__ b, float* __restrict__ out, int n) {
    int idx = blockIdx.x * 256 + threadIdx.x;
    int nd = idx >> 5, lane = idx & 31;
    if (nd >= n) return;
    float v = acc[idx] * 0.125f + b[lane];
    float m = v;
    for (int off = 16; off; off >>= 1) m = fmaxf(m, __shfl_xor(m, off, 32));
    float exv = __expf(v - m);
    float ssum = exv;
    for (int off = 16; off; off >>= 1) ssum += __shfl_xor(ssum, off, 32);
    out[idx] = v - m - logf(ssum);
}

// ---------------- launch ----------------
extern "C" void kernel_launch(void* const* d_in, const int* in_sizes, int n_in,
                              void* d_out, int out_size, void* d_ws, size_t ws_size,
                              hipStream_t stream) {
    const float* x        = (const float*)d_in[0];
    const int*   eidx     = (const int*)d_in[1];
    const float* gcn1_w   = (const float*)d_in[2];
    const float* gcn1_b   = (const float*)d_in[3];
    const float* bn1_g    = (const float*)d_in[4];
    const float* bn1_b    = (const float*)d_in[5];
    const float* bn1_m    = (const float*)d_in[6];
    const float* bn1_v    = (const float*)d_in[7];
    const float* gat1_w   = (const float*)d_in[8];
    const float* gat1_as  = (const float*)d_in[9];
    const float* gat1_ad  = (const float*)d_in[10];
    const float* gat1_b   = (const float*)d_in[11];
    const float* gcn2_w   = (const float*)d_in[12];
    const float* gcn2_b   = (const float*)d_in[13];
    const float* bn2_g    = (const float*)d_in[14];
    const float* bn2_b    = (const float*)d_in[15];
    const float* bn2_m    = (const float*)d_in[16];
    const float* bn2_v    = (const float*)d_in[17];
    const float* gat2_w   = (const float*)d_in[18];
    const float* gat2_as  = (const float*)d_in[19];
    const float* gat2_ad  = (const float*)d_in[20];
    const float* gat2_b   = (const float*)d_in[21];
    float* out = (float*)d_out;

    const int* esrc = eidx;
    const int* edst = eidx + NE;

    // workspace (~84 MB, < proven-safe 110.6 MB)
    float* ws = (float*)d_ws;
    int*   cnt    = (int*)ws;                         // 50048
    int*   rowptr = cnt + 50048;                      // 50048
    int*   cursor = rowptr + 50048;                   // 50048
    int*   csrc   = cursor + 50048;                   // 800000
    float* dinv   = (float*)(csrc + 800000);          // 50048
    float* es     = dinv + 50048;                     // 400000
    float* ed     = es + 400000;                      // 400000
    float* was    = ed + 400000;                      // 512
    float* wad    = was + 512;                        // 512
    int*   bsum   = (int*)(wad + 512);                // 256
    int*   pre    = bsum + 256;                       // 50048
    float* wprime = (float*)(pre + 50048);            // 512*64
    float* buf32  = wprime + 512 * 64;                // N*32 f32
    bf16*  actb   = (bf16*)(buf32 + (size_t)NN * 32); // N*64 bf16
    bf16*  mmbf   = actb + (size_t)NN * 64;           // N*64 bf16
    bf16*  agg    = mmbf + (size_t)NN * 64;           // N*512 bf16

    auto cdiv = [](long a, long b) { return (int)((a + b - 1) / b); };
    const int GB = cdiv(NN, 64);       // 782 row-blocks for matmuls
    const int NB = cdiv(NN, 4);        // 12500 node-blocks (wave per node)

    // ---- CSR build (hierarchical scan) ----
    zero_int_kernel<<<cdiv(NN, 256), 256, 0, stream>>>(cnt, NN);
    hist_kernel<<<cdiv(NE, 256), 256, 0, stream>>>(edst, cnt, NE);
    scan1_kernel<<<NBLK, 256, 0, stream>>>(cnt, pre, bsum);
    scan2_kernel<<<1, 256, 0, stream>>>(bsum);
    scan3_kernel<<<NBLK, 256, 0, stream>>>(pre, bsum, cnt, rowptr, cursor, dinv);
    scatter_kernel<<<cdiv(NE, 256), 256, 0, stream>>>(esrc, edst, cursor, csrc, NE);

    // ---- GCN1 ----
    mm_kernel<IND, false, 3><<<dim3(GB, 1), 256, 0, stream>>>(x, gcn1_w, mmbf, nullptr, dinv, NN, 64);
    gcn_fused_kernel<<<NB, 256, 0, stream>>>(rowptr, csrc, dinv, mmbf,
        gcn1_b, bn1_g, bn1_b, bn1_m, bn1_v, actb);

    // ---- GAT1 (C=64): scores from act, aggregate in act-space, then project ----
    proj_aw_kernel<64><<<2, 256, 0, stream>>>(gat1_w, gat1_as, gat1_ad, was, wad);
    scores_kernel<<<NB, 256, 0, stream>>>(actb, was, wad, es, ed, NN);
    gat_agg_kernel<<<NB, 256, 0, stream>>>(rowptr, csrc, es, ed, actb, agg);
    reshape_w_kernel<64><<<cdiv(512 * 64, 256), 256, 0, stream>>>(gat1_w, wprime);
    mm_kernel<512, true, 2><<<dim3(GB, 1), 256, 0, stream>>>(agg, wprime, actb, gat1_b, nullptr, NN, 64);

    // ---- GCN2 ----
    mm_kernel<64, true, 3><<<dim3(GB, 1), 256, 0, stream>>>(actb, gcn2_w, mmbf, nullptr, dinv, NN, 64);
    gcn_fused_kernel<<<NB, 256, 0, stream>>>(rowptr, csrc, dinv, mmbf,
        gcn2_b, bn2_g, bn2_b, bn2_m, bn2_v, actb);

    // ---- GAT2 (C=32) ----
    proj_aw_kernel<32><<<2, 256, 0, stream>>>(gat2_w, gat2_as, gat2_ad, was, wad);
    scores_kernel<<<NB, 256, 0, stream>>>(actb, was, wad, es, ed, NN);
    gat_agg_kernel<<<NB, 256, 0, stream>>>(rowptr, csrc, es, ed, actb, agg);
    reshape_w_kernel<32><<<cdiv(512 * 32, 256), 256, 0, stream>>>(gat2_w, wprime);
    mm_kernel<512, true, 0><<<dim3(GB, 1), 256, 0, stream>>>(agg, wprime, buf32, nullptr, nullptr, NN, 32);

    // ---- log_softmax -> fp32 out ----
    logsoftmax_kernel<<<cdiv((long)NN * 32, 256), 256, 0, stream>>>(buf32, gat2_b, out, NN);
}

// Round 13
// 453.761 us; speedup vs baseline: 1.7189x; 1.1214x over previous
//
#include <hip/hip_runtime.h>
#include <hip/hip_bf16.h>

#define NN 50000
#define NE 800000
#define IND 128
#define NH 8
#define EBLK 256          // binning blocks
#define EPB 3125          // NE / EBLK
#define NBUK 391          // buckets of 128 dst nodes (50000>>7 = 390)
#define NBUKP 392         // padded (bucket 391 empty -> its offset == NE)
#define GH (NBUKP * EBLK) // 100352 (bucket-major (bucket, block) counts)

typedef __hip_bfloat16 bf16;
typedef __attribute__((ext_vector_type(8))) short short8;
typedef __attribute__((ext_vector_type(8))) __bf16 bf16x8;
typedef __attribute__((ext_vector_type(4))) float floatx4;

// float -> bf16 bits, round-to-nearest-even (finite inputs only)
static __device__ __forceinline__ short f2bf_bits(float f) {
    unsigned u = __float_as_uint(f);
    u = (u + 0x7fffu + ((u >> 16) & 1u)) >> 16;
    return (short)u;
}
static __device__ __forceinline__ float bf2f(bf16 v) { return __bfloat162float(v); }

// ---------------- CSR build: two-level counting sort (no random global writes) ----------------
// Pass A: per-(bucket, block) histogram via LDS — replaces 800K random global atomics.
__global__ __launch_bounds__(256) void bin_count_kernel(const int* __restrict__ edst,
        int* __restrict__ ghist) {
    __shared__ int h[NBUKP];
    const int tid = threadIdx.x, blk = blockIdx.x;
    for (int b = tid; b < NBUKP; b += 256) h[b] = 0;
    __syncthreads();
    const int e0 = blk * EPB;
    for (int e = e0 + tid; e < e0 + EPB; e += 256)
        atomicAdd(&h[edst[e] >> 7], 1);
    __syncthreads();
    for (int b = tid; b < NBUKP; b += 256)
        ghist[b * EBLK + blk] = h[b];
}
// generic hierarchical exclusive scan (n elements)
__global__ __launch_bounds__(256) void scang1_kernel(const int* __restrict__ src,
        int* __restrict__ pre, int* __restrict__ bsum, int n) {
    __shared__ int sh[256];
    const int tid = threadIdx.x;
    const int idx = blockIdx.x * 256 + tid;
    int c = (idx < n) ? src[idx] : 0;
    sh[tid] = c; __syncthreads();
    int val = c;
#pragma unroll
    for (int off = 1; off < 256; off <<= 1) {
        int t = (tid >= off) ? sh[tid - off] : 0;
        __syncthreads();
        val += t; sh[tid] = val;
        __syncthreads();
    }
    if (idx < n) pre[idx] = val - c;
    if (tid == 255) bsum[blockIdx.x] = val;
}
__global__ __launch_bounds__(512) void scang2_kernel(int* __restrict__ bsum, int nb) {
    __shared__ int sh[512];
    const int tid = threadIdx.x;
    int v = (tid < nb) ? bsum[tid] : 0;
    sh[tid] = v; __syncthreads();
    int val = v;
#pragma unroll
    for (int off = 1; off < 512; off <<= 1) {
        int t = (tid >= off) ? sh[tid - off] : 0;
        __syncthreads();
        val += t; sh[tid] = val;
        __syncthreads();
    }
    if (tid < nb) bsum[tid] = val - v;
}
__global__ __launch_bounds__(256) void scang3_kernel(const int* __restrict__ pre,
        const int* __restrict__ bsum, int* __restrict__ dst, int n) {
    const int idx = blockIdx.x * 256 + threadIdx.x;
    if (idx < n) dst[idx] = pre[idx] + bsum[idx >> 8];
}
// Pass C: scatter into bucket-segmented regions via LDS cursors (runs ~8 -> ~2x write amp)
__global__ __launch_bounds__(256) void bin_scatter_kernel(const int* __restrict__ esrc,
        const int* __restrict__ edst, const int* __restrict__ goff, unsigned* __restrict__ ebuf) {
    __shared__ int cur[NBUKP];
    const int tid = threadIdx.x, blk = blockIdx.x;
    for (int b = tid; b < NBUKP; b += 256) cur[b] = goff[b * EBLK + blk];
    __syncthreads();
    const int e0 = blk * EPB;
    for (int e = e0 + tid; e < e0 + EPB; e += 256) {
        int d = edst[e], s = esrc[e];
        int pos = atomicAdd(&cur[d >> 7], 1);
        ebuf[pos] = ((unsigned)(d & 127) << 16) | (unsigned)s;   // src < 65536
    }
}
// Pass D: per-bucket counting sort -> final csrc (contiguous 8KB region), rowptr, dinv
__global__ __launch_bounds__(256) void bucket_finalize_kernel(const unsigned* __restrict__ ebuf,
        const int* __restrict__ goff, int* __restrict__ rowptr, float* __restrict__ dinv,
        int* __restrict__ csrc) {
    __shared__ int lh[128], lcur[128], sc[256];
    const int bu = blockIdx.x, tid = threadIdx.x;
    const int seg_beg = goff[bu * EBLK];
    const int seg_end = goff[(bu + 1) * EBLK];   // bucket NBUK-1 reads empty bucket 391 -> NE
    if (tid < 128) lh[tid] = 0;
    __syncthreads();
    for (int i = seg_beg + tid; i < seg_end; i += 256)
        atomicAdd(&lh[ebuf[i] >> 16], 1);
    __syncthreads();
    int c = (tid < 128) ? lh[tid] : 0;
    sc[tid] = c; __syncthreads();
    int val = c;
#pragma unroll
    for (int off = 1; off < 256; off <<= 1) {
        int t = (tid >= off) ? sc[tid - off] : 0;
        __syncthreads();
        val += t; sc[tid] = val;
        __syncthreads();
    }
    int excl = val - c;
    if (tid < 128) {
        lcur[tid] = excl;
        int node = bu * 128 + tid;
        if (node < NN) {
            rowptr[node] = seg_beg + excl;
            dinv[node] = rsqrtf((float)c + 1.f);
        }
    }
    if (bu == 0 && tid == 0) rowptr[NN] = NE;
    __syncthreads();
    for (int i = seg_beg + tid; i < seg_end; i += 256) {
        unsigned u = ebuf[i];
        int pos = atomicAdd(&lcur[u >> 16], 1);
        csrc[seg_beg + pos] = (int)(u & 0xffffu);
    }
}

// ---------------- MFMA matmul: C[n,M] = A[n,K] @ W[K,M] ----------------
// K-chunked LDS staging (BK=128). W fp32; A fp32 or bf16 (ABF16).
// EPI 0: raw fp32; 1: plain bf16; 2: bf16 relu(v*0.125+bias[col]); 3: bf16 rowscale[row]*v.
template<int K, bool ABF16, int EPI>
__global__ __launch_bounds__(256) void mm_kernel(const void* __restrict__ A,
        const float* __restrict__ W, void* __restrict__ C,
        const float* __restrict__ bias, const float* __restrict__ rowscale,
        int nrows, int M) {
    constexpr int BK = (K > 128) ? 128 : K;
    __shared__ __align__(16) short Alds[64][BK + 8];
    __shared__ __align__(16) short Wlds[64][BK + 8];   // transposed: Wlds[m][k]
    const int row0 = blockIdx.x * 64;
    const int m0   = blockIdx.y * 64;
    const int tid  = threadIdx.x;
    const int lane = tid & 63, wave = tid >> 6;
    const int lr = lane & 15, q = lane >> 4;
    const int rw = wave * 16;
    floatx4 acc[4] = {};

    for (int kc = 0; kc < K; kc += BK) {
        if (kc) __syncthreads();
        constexpr int KB = BK / 8;
        for (int i = tid; i < 64 * KB; i += 256) {
            int r = i / KB, kb = i % KB;
            int row = row0 + r;
            short8 v = {0, 0, 0, 0, 0, 0, 0, 0};
            if (row < nrows) {
                if (ABF16) {
                    v = *(const short8*)((const short*)A + (long)row * K + kc + kb * 8);
                } else {
                    const float* ap = (const float*)A + (long)row * K + kc + kb * 8;
                    floatx4 va = *(const floatx4*)ap;
                    floatx4 vb = *(const floatx4*)(ap + 4);
#pragma unroll
                    for (int j = 0; j < 4; ++j) { v[j] = f2bf_bits(va[j]); v[4 + j] = f2bf_bits(vb[j]); }
                }
            }
            *(short8*)&Alds[r][kb * 8] = v;
        }
        for (int i = tid; i < BK * 64; i += 256) {
            int k = i >> 6, m = i & 63;
            Wlds[m][k] = (m0 + m < M) ? f2bf_bits(W[(long)(kc + k) * M + m0 + m]) : (short)0;
        }
        __syncthreads();
#pragma unroll
        for (int k0 = 0; k0 < BK; k0 += 32) {
            bf16x8 a = __builtin_bit_cast(bf16x8, *(const short8*)&Alds[rw + lr][k0 + q * 8]);
#pragma unroll
            for (int c = 0; c < 4; ++c) {
                bf16x8 b = __builtin_bit_cast(bf16x8, *(const short8*)&Wlds[c * 16 + lr][k0 + q * 8]);
                acc[c] = __builtin_amdgcn_mfma_f32_16x16x32_bf16(a, b, acc[c], 0, 0, 0);
            }
        }
    }
#pragma unroll
    for (int c = 0; c < 4; ++c)
#pragma unroll
        for (int r = 0; r < 4; ++r) {
            int row = row0 + rw + q * 4 + r;
            int col = m0 + c * 16 + lr;
            if (row < nrows && col < M) {
                long o = (long)row * M + col;
                float v = acc[c][r];
                if (EPI == 0) ((float*)C)[o] = v;
                else if (EPI == 1) ((bf16*)C)[o] = __float2bfloat16(v);
                else if (EPI == 2) {
                    v = v * 0.125f + bias[col];
                    ((bf16*)C)[o] = __float2bfloat16(fmaxf(v, 0.f));
                } else {
                    ((bf16*)C)[o] = __float2bfloat16(rowscale[row] * v);
                }
            }
        }
}

// ---------------- fused GCN aggregate + bias + BN + ReLU (CSR, no atomics) ----------------
// hin rows are PREMULTIPLIED by dinv[row] (mm EPI=3) -> per edge: 1 row gather + 1 add.
__global__ __launch_bounds__(256) void gcn_fused_kernel(const int* __restrict__ rowptr,
        const int* __restrict__ csrc, const float* __restrict__ dinv,
        const bf16* __restrict__ hin, const float* __restrict__ b,
        const float* __restrict__ gamma, const float* __restrict__ beta,
        const float* __restrict__ mean, const float* __restrict__ var,
        bf16* __restrict__ actout) {
    const int node = blockIdx.x * 4 + (threadIdx.x >> 6);
    if (node >= NN) return;
    const int lane = threadIdx.x & 63;
    const int beg = rowptr[node], end = rowptr[node + 1];
    const float di = dinv[node];
    float acc = bf2f(hin[(long)node * 64 + lane]);   // self: h' already has di factor
    int ei = beg;
    for (; ei + 4 <= end; ei += 4) {
        int s0 = csrc[ei], s1 = csrc[ei + 1], s2 = csrc[ei + 2], s3 = csrc[ei + 3];
        float h0 = bf2f(hin[(long)s0 * 64 + lane]);
        float h1 = bf2f(hin[(long)s1 * 64 + lane]);
        float h2 = bf2f(hin[(long)s2 * 64 + lane]);
        float h3 = bf2f(hin[(long)s3 * 64 + lane]);
        acc += (h0 + h1) + (h2 + h3);
    }
    for (; ei < end; ++ei) {
        int s = csrc[ei];
        acc += bf2f(hin[(long)s * 64 + lane]);
    }
    float x = acc * di + b[lane];
    x = (x - mean[lane]) * rsqrtf(var[lane] + 1e-5f) * gamma[lane] + beta[lane];
    actout[(long)node * 64 + lane] = __float2bfloat16(fmaxf(x, 0.f));
}

// ---------------- attention prep: project a-vectors through W ----------------
template<int C>
__global__ void proj_aw_kernel(const float* __restrict__ W, const float* __restrict__ as,
        const float* __restrict__ ad, float* __restrict__ was, float* __restrict__ wad) {
    int idx = blockIdx.x * 256 + threadIdx.x;
    if (idx >= 512) return;
    int h = idx >> 6, c = idx & 63;
    const float* wrow = W + (long)c * (NH * C) + h * C;
    float s = 0.f, d = 0.f;
    for (int cc = 0; cc < C; ++cc) {
        float w = wrow[cc];
        s += w * as[h * C + cc];
        d += w * ad[h * C + cc];
    }
    was[idx] = s; wad[idx] = d;
}
// wp[(h*64+c)*C + c'] = W[c][h*C+c']
template<int C>
__global__ void reshape_w_kernel(const float* __restrict__ W, float* __restrict__ wp) {
    int idx = blockIdx.x * 256 + threadIdx.x;
    if (idx >= 512 * C) return;
    int kk = idx / C, cp = idx % C;
    int h = kk >> 6, c = kk & 63;
    wp[idx] = W[(long)c * (NH * C) + h * C + cp];
}
// es[n,h] = <act[n,:], was[h,:]> — wave per node, lanes=(h=lane>>3, cg=lane&7)
__global__ __launch_bounds__(256) void scores_kernel(const bf16* __restrict__ actb,
        const float* __restrict__ was, const float* __restrict__ wad,
        float* __restrict__ es, float* __restrict__ ed, int n) {
    const int node = blockIdx.x * 4 + (threadIdx.x >> 6);
    if (node >= n) return;
    const int lane = threadIdx.x & 63;
    const int h = lane >> 3, cg = lane & 7;
    short8 a8 = *(const short8*)((const short*)actb + (long)node * 64 + cg * 8);
    const float* wsp = was + h * 64 + cg * 8;
    const float* wdp = wad + h * 64 + cg * 8;
    floatx4 ws0 = *(const floatx4*)wsp, ws1 = *(const floatx4*)(wsp + 4);
    floatx4 wd0 = *(const floatx4*)wdp, wd1 = *(const floatx4*)(wdp + 4);
    float s = 0.f, d = 0.f;
#pragma unroll
    for (int j = 0; j < 4; ++j) {
        float v0 = bf2f(__builtin_bit_cast(bf16, a8[j]));
        float v1 = bf2f(__builtin_bit_cast(bf16, a8[4 + j]));
        s += v0 * ws0[j] + v1 * ws1[j];
        d += v0 * wd0[j] + v1 * wd1[j];
    }
#pragma unroll
    for (int off = 1; off < 8; off <<= 1) {
        s += __shfl_xor(s, off);
        d += __shfl_xor(d, off);
    }
    if (cg == 0) { es[node * NH + h] = s; ed[node * NH + h] = d; }
}

// ---------------- GAT aggregation in act-space (CSR, no atomics) ----------------
// Softmax shifted by the SELF logit (exact: alpha_j = exp(e_j-selfe)/(sum+1)) — no online-max
// chain, no Phase-B exps. Fast path (deg<=64): register exps, all alphas staged to LDS once,
// single fully-independent gather loop.
__global__ __launch_bounds__(256) void gat_agg_kernel(const int* __restrict__ rowptr,
        const int* __restrict__ csrc, const float* __restrict__ es, const float* __restrict__ ed,
        const bf16* __restrict__ actb, bf16* __restrict__ agg) {
    __shared__ __align__(16) float salpha[4][512];
    __shared__ int ssrcs[4][64];
    __shared__ __align__(16) float sself[4][8];
    const int wv = threadIdx.x >> 6;
    const int node = blockIdx.x * 4 + wv;
    if (node >= NN) return;
    const int lane = threadIdx.x & 63;
    const int h = lane & 7, slot = lane >> 3;
    const int beg = rowptr[node], end = rowptr[node + 1];
    const int deg = end - beg;
    const float edr = ed[node * NH + h];

    float selfe = es[node * NH + h] + edr;
    selfe = selfe > 0.f ? selfe : 0.2f * selfe;

    float acc[NH] = {0.f, 0.f, 0.f, 0.f, 0.f, 0.f, 0.f, 0.f};

    if (deg <= 64) {
        float ex_r[8]; int s_r[8];
        float den = 0.f;
#pragma unroll
        for (int b = 0; b < 8; ++b) {
            ex_r[b] = 0.f; s_r[b] = 0;
            int k = b * 8 + slot;
            if (k < deg) {
                int s = csrc[beg + k];
                s_r[b] = s;
                float e = es[s * NH + h] + edr;
                e = e > 0.f ? e : 0.2f * e;
                ex_r[b] = __expf(e - selfe);
                den += ex_r[b];
            }
        }
        den += __shfl_xor(den, 8);
        den += __shfl_xor(den, 16);
        den += __shfl_xor(den, 32);
        const float invden = 1.f / (den + 1.f);   // +1 = self term

#pragma unroll
        for (int b = 0; b < 8; ++b)
            salpha[wv][b * 64 + lane] = ex_r[b] * invden;
        if (h == 0) {
#pragma unroll
            for (int b = 0; b < 8; ++b)
                ssrcs[wv][b * 8 + slot] = s_r[b];
        }
        if (slot == 0) sself[wv][h] = invden;

#pragma unroll 4
        for (int k = 0; k < deg; ++k) {
            int s = ssrcs[wv][k];
            float a = bf2f(actb[(long)s * 64 + lane]);
            const float* ap = &salpha[wv][(k >> 3) * 64 + (k & 7) * 8];
            floatx4 al0 = *(const floatx4*)ap;
            floatx4 al1 = *(const floatx4*)(ap + 4);
            acc[0] += al0[0] * a; acc[1] += al0[1] * a;
            acc[2] += al0[2] * a; acc[3] += al0[3] * a;
            acc[4] += al1[0] * a; acc[5] += al1[1] * a;
            acc[6] += al1[2] * a; acc[7] += al1[3] * a;
        }
        {   // self
            float a = bf2f(actb[(long)node * 64 + lane]);
            floatx4 s0 = *(const floatx4*)&sself[wv][0];
            floatx4 s1 = *(const floatx4*)&sself[wv][4];
            acc[0] += s0[0] * a; acc[1] += s0[1] * a;
            acc[2] += s0[2] * a; acc[3] += s0[3] * a;
            acc[4] += s1[0] * a; acc[5] += s1[1] * a;
            acc[6] += s1[2] * a; acc[7] += s1[3] * a;
        }
    } else {
        // fallback (deg>64, rare): streaming two-pass with self-shift
        float den = 0.f;
        for (int base = beg; base < end; base += 8) {
            int ei = base + slot;
            if (ei < end) {
                int s = csrc[ei];
                float e = es[s * NH + h] + edr;
                e = e > 0.f ? e : 0.2f * e;
                den += __expf(e - selfe);
            }
        }
        den += __shfl_xor(den, 8);
        den += __shfl_xor(den, 16);
        den += __shfl_xor(den, 32);
        const float invden = 1.f / (den + 1.f);
        for (int base = beg; base < end; base += 8) {
            int ei = base + slot;
            float al = 0.f; int sl = 0;
            if (ei < end) {
                sl = csrc[ei];
                float e = es[sl * NH + h] + edr;
                e = e > 0.f ? e : 0.2f * e;
                al = __expf(e - selfe) * invden;
            }
            salpha[wv][lane] = al;
            if (h == 0) ssrcs[wv][slot] = sl;
            int ecnt = end - base; if (ecnt > 8) ecnt = 8;
            for (int j = 0; j < ecnt; ++j) {
                int s = ssrcs[wv][j];
                float a = bf2f(actb[(long)s * 64 + lane]);
                floatx4 al0 = *(const floatx4*)&salpha[wv][j * 8];
                floatx4 al1 = *(const floatx4*)&salpha[wv][j * 8 + 4];
                acc[0] += al0[0] * a; acc[1] += al0[1] * a;
                acc[2] += al0[2] * a; acc[3] += al0[3] * a;
                acc[4] += al1[0] * a; acc[5] += al1[1] * a;
                acc[6] += al1[2] * a; acc[7] += al1[3] * a;
            }
        }
        {
            if (slot == 0) sself[wv][h] = invden;
            float a = bf2f(actb[(long)node * 64 + lane]);
            floatx4 s0 = *(const floatx4*)&sself[wv][0];
            floatx4 s1 = *(const floatx4*)&sself[wv][4];
            acc[0] += s0[0] * a; acc[1] += s0[1] * a;
            acc[2] += s0[2] * a; acc[3] += s0[3] * a;
            acc[4] += s1[0] * a; acc[5] += s1[1] * a;
            acc[6] += s1[2] * a; acc[7] += s1[3] * a;
        }
    }
#pragma unroll
    for (int hh = 0; hh < NH; ++hh)
        agg[(long)node * 512 + hh * 64 + lane] = __float2bfloat16(acc[hh]);
}

// ---------------- final log_softmax (32 cols) ----------------
__global__ __launch_bounds__(256) void logsoftmax_kernel(const float* __restrict__ acc,
        const float* __restrict__ b, float* __restrict__ out, int n) {
    int idx = blockIdx.x * 256 + threadIdx.x;
    int nd = idx >> 5, lane = idx & 31;
    if (nd >= n) return;
    float v = acc[idx] * 0.125f + b[lane];
    float m = v;
    for (int off = 16; off; off >>= 1) m = fmaxf(m, __shfl_xor(m, off, 32));
    float exv = __expf(v - m);
    float ssum = exv;
    for (int off = 16; off; off >>= 1) ssum += __shfl_xor(ssum, off, 32);
    out[idx] = v - m - logf(ssum);
}

// ---------------- launch ----------------
extern "C" void kernel_launch(void* const* d_in, const int* in_sizes, int n_in,
                              void* d_out, int out_size, void* d_ws, size_t ws_size,
                              hipStream_t stream) {
    const float* x        = (const float*)d_in[0];
    const int*   eidx     = (const int*)d_in[1];
    const float* gcn1_w   = (const float*)d_in[2];
    const float* gcn1_b   = (const float*)d_in[3];
    const float* bn1_g    = (const float*)d_in[4];
    const float* bn1_b    = (const float*)d_in[5];
    const float* bn1_m    = (const float*)d_in[6];
    const float* bn1_v    = (const float*)d_in[7];
    const float* gat1_w   = (const float*)d_in[8];
    const float* gat1_as  = (const float*)d_in[9];
    const float* gat1_ad  = (const float*)d_in[10];
    const float* gat1_b   = (const float*)d_in[11];
    const float* gcn2_w   = (const float*)d_in[12];
    const float* gcn2_b   = (const float*)d_in[13];
    const float* bn2_g    = (const float*)d_in[14];
    const float* bn2_b    = (const float*)d_in[15];
    const float* bn2_m    = (const float*)d_in[16];
    const float* bn2_v    = (const float*)d_in[17];
    const float* gat2_w   = (const float*)d_in[18];
    const float* gat2_as  = (const float*)d_in[19];
    const float* gat2_ad  = (const float*)d_in[20];
    const float* gat2_b   = (const float*)d_in[21];
    float* out = (float*)d_out;

    const int* esrc = eidx;
    const int* edst = eidx + NE;

    // workspace (~85 MB, < proven-safe 110.6 MB)
    float* ws = (float*)d_ws;
    int*      ghist  = (int*)ws;                        // GH
    int*      gpre   = ghist + GH;                      // GH
    int*      gbsum  = gpre + GH;                       // 512
    unsigned* ebuf   = (unsigned*)(gbsum + 512);        // NE
    int*      rowptr = (int*)(ebuf + NE);               // 50048
    int*      csrc   = rowptr + 50048;                  // NE
    float*    dinv   = (float*)(csrc + NE);             // 50048
    float*    es     = dinv + 50048;                    // 400000
    float*    ed     = es + 400000;                     // 400000
    float*    was    = ed + 400000;                     // 512
    float*    wad    = was + 512;                       // 512
    float*    wprime = wad + 512;                       // 512*64
    float*    buf32  = wprime + 512 * 64;               // N*32 f32
    bf16*     actb   = (bf16*)(buf32 + (size_t)NN * 32);// N*64 bf16
    bf16*     mmbf   = actb + (size_t)NN * 64;          // N*64 bf16
    bf16*     agg    = mmbf + (size_t)NN * 64;          // N*512 bf16

    auto cdiv = [](long a, long b) { return (int)((a + b - 1) / b); };
    const int GB = cdiv(NN, 64);       // 782 row-blocks for matmuls
    const int NB = cdiv(NN, 4);        // 12500 node-blocks (wave per node)

    // ---- CSR build: two-level counting sort ----
    bin_count_kernel<<<EBLK, 256, 0, stream>>>(edst, ghist);
    scang1_kernel<<<GH / 256, 256, 0, stream>>>(ghist, gpre, gbsum, GH);
    scang2_kernel<<<1, 512, 0, stream>>>(gbsum, GH / 256);
    scang3_kernel<<<GH / 256, 256, 0, stream>>>(gpre, gbsum, ghist, GH);   // ghist := scanned
    bin_scatter_kernel<<<EBLK, 256, 0, stream>>>(esrc, edst, ghist, ebuf);
    bucket_finalize_kernel<<<NBUK, 256, 0, stream>>>(ebuf, ghist, rowptr, dinv, csrc);

    // ---- GCN1 ----
    mm_kernel<IND, false, 3><<<dim3(GB, 1), 256, 0, stream>>>(x, gcn1_w, mmbf, nullptr, dinv, NN, 64);
    gcn_fused_kernel<<<NB, 256, 0, stream>>>(rowptr, csrc, dinv, mmbf,
        gcn1_b, bn1_g, bn1_b, bn1_m, bn1_v, actb);

    // ---- GAT1 (C=64): scores from act, aggregate in act-space, then project ----
    proj_aw_kernel<64><<<2, 256, 0, stream>>>(gat1_w, gat1_as, gat1_ad, was, wad);
    scores_kernel<<<NB, 256, 0, stream>>>(actb, was, wad, es, ed, NN);
    gat_agg_kernel<<<NB, 256, 0, stream>>>(rowptr, csrc, es, ed, actb, agg);
    reshape_w_kernel<64><<<cdiv(512 * 64, 256), 256, 0, stream>>>(gat1_w, wprime);
    mm_kernel<512, true, 2><<<dim3(GB, 1), 256, 0, stream>>>(agg, wprime, actb, gat1_b, nullptr, NN, 64);

    // ---- GCN2 ----
    mm_kernel<64, true, 3><<<dim3(GB, 1), 256, 0, stream>>>(actb, gcn2_w, mmbf, nullptr, dinv, NN, 64);
    gcn_fused_kernel<<<NB, 256, 0, stream>>>(rowptr, csrc, dinv, mmbf,
        gcn2_b, bn2_g, bn2_b, bn2_m, bn2_v, actb);

    // ---- GAT2 (C=32) ----
    proj_aw_kernel<32><<<2, 256, 0, stream>>>(gat2_w, gat2_as, gat2_ad, was, wad);
    scores_kernel<<<NB, 256, 0, stream>>>(actb, was, wad, es, ed, NN);
    gat_agg_kernel<<<NB, 256, 0, stream>>>(rowptr, csrc, es, ed, actb, agg);
    reshape_w_kernel<32><<<cdiv(512 * 32, 256), 256, 0, stream>>>(gat2_w, wprime);
    mm_kernel<512, true, 0><<<dim3(GB, 1), 256, 0, stream>>>(agg, wprime, buf32, nullptr, nullptr, NN, 32);

    // ---- log_softmax -> fp32 out ----
    logsoftmax_kernel<<<cdiv((long)NN * 32, 256), 256, 0, stream>>>(buf32, gat2_b, out, NN);
}

// Round 14
// 443.695 us; speedup vs baseline: 1.7579x; 1.0227x over previous
//
#include <hip/hip_runtime.h>
#include <hip/hip_bf16.h>

#define NN 50000
#define NE 800000
#define IND 128
#define NH 8
#define EBLK 256          // binning blocks
#define EPB 3125          // NE / EBLK
#define NBUK 391          // buckets of 128 dst nodes
#define NBUKP 392         // padded (bucket 391 empty -> offset == NE)
#define GH (NBUKP * EBLK) // 100352

typedef __hip_bfloat16 bf16;
typedef __attribute__((ext_vector_type(8))) short short8;
typedef __attribute__((ext_vector_type(8))) __bf16 bf16x8;
typedef __attribute__((ext_vector_type(4))) float floatx4;

static __device__ __forceinline__ short f2bf_bits(float f) {
    unsigned u = __float_as_uint(f);
    u = (u + 0x7fffu + ((u >> 16) & 1u)) >> 16;
    return (short)u;
}
static __device__ __forceinline__ float bf2f(bf16 v) { return __bfloat162float(v); }

// ---------------- CSR build: two-level counting sort ----------------
__global__ __launch_bounds__(256) void bin_count_kernel(const int* __restrict__ edst,
        int* __restrict__ ghist) {
    __shared__ int h[NBUKP];
    const int tid = threadIdx.x, blk = blockIdx.x;
    for (int b = tid; b < NBUKP; b += 256) h[b] = 0;
    __syncthreads();
    const int e0 = blk * EPB;
    for (int e = e0 + tid; e < e0 + EPB; e += 256)
        atomicAdd(&h[edst[e] >> 7], 1);
    __syncthreads();
    for (int b = tid; b < NBUKP; b += 256)
        ghist[b * EBLK + blk] = h[b];
}
__global__ __launch_bounds__(256) void scang1_kernel(const int* __restrict__ src,
        int* __restrict__ pre, int* __restrict__ bsum, int n) {
    __shared__ int sh[256];
    const int tid = threadIdx.x;
    const int idx = blockIdx.x * 256 + tid;
    int c = (idx < n) ? src[idx] : 0;
    sh[tid] = c; __syncthreads();
    int val = c;
#pragma unroll
    for (int off = 1; off < 256; off <<= 1) {
        int t = (tid >= off) ? sh[tid - off] : 0;
        __syncthreads();
        val += t; sh[tid] = val;
        __syncthreads();
    }
    if (idx < n) pre[idx] = val - c;
    if (tid == 255) bsum[blockIdx.x] = val;
}
__global__ __launch_bounds__(512) void scang2_kernel(int* __restrict__ bsum, int nb) {
    __shared__ int sh[512];
    const int tid = threadIdx.x;
    int v = (tid < nb) ? bsum[tid] : 0;
    sh[tid] = v; __syncthreads();
    int val = v;
#pragma unroll
    for (int off = 1; off < 512; off <<= 1) {
        int t = (tid >= off) ? sh[tid - off] : 0;
        __syncthreads();
        val += t; sh[tid] = val;
        __syncthreads();
    }
    if (tid < nb) bsum[tid] = val - v;
}
__global__ __launch_bounds__(256) void scang3_kernel(const int* __restrict__ pre,
        const int* __restrict__ bsum, int* __restrict__ dst, int n) {
    const int idx = blockIdx.x * 256 + threadIdx.x;
    if (idx < n) dst[idx] = pre[idx] + bsum[idx >> 8];
}
__global__ __launch_bounds__(256) void bin_scatter_kernel(const int* __restrict__ esrc,
        const int* __restrict__ edst, const int* __restrict__ goff, unsigned* __restrict__ ebuf) {
    __shared__ int cur[NBUKP];
    const int tid = threadIdx.x, blk = blockIdx.x;
    for (int b = tid; b < NBUKP; b += 256) cur[b] = goff[b * EBLK + blk];
    __syncthreads();
    const int e0 = blk * EPB;
    for (int e = e0 + tid; e < e0 + EPB; e += 256) {
        int d = edst[e], s = esrc[e];
        int pos = atomicAdd(&cur[d >> 7], 1);
        ebuf[pos] = ((unsigned)(d & 127) << 16) | (unsigned)s;
    }
}
__global__ __launch_bounds__(256) void bucket_finalize_kernel(const unsigned* __restrict__ ebuf,
        const int* __restrict__ goff, int* __restrict__ rowptr, float* __restrict__ dinv,
        int* __restrict__ csrc) {
    __shared__ int lh[128], lcur[128], sc[256];
    const int bu = blockIdx.x, tid = threadIdx.x;
    const int seg_beg = goff[bu * EBLK];
    const int seg_end = goff[(bu + 1) * EBLK];
    if (tid < 128) lh[tid] = 0;
    __syncthreads();
    for (int i = seg_beg + tid; i < seg_end; i += 256)
        atomicAdd(&lh[ebuf[i] >> 16], 1);
    __syncthreads();
    int c = (tid < 128) ? lh[tid] : 0;
    sc[tid] = c; __syncthreads();
    int val = c;
#pragma unroll
    for (int off = 1; off < 256; off <<= 1) {
        int t = (tid >= off) ? sc[tid - off] : 0;
        __syncthreads();
        val += t; sc[tid] = val;
        __syncthreads();
    }
    int excl = val - c;
    if (tid < 128) {
        lcur[tid] = excl;
        int node = bu * 128 + tid;
        if (node < NN) {
            rowptr[node] = seg_beg + excl;
            dinv[node] = rsqrtf((float)c + 1.f);
        }
    }
    if (bu == 0 && tid == 0) rowptr[NN] = NE;
    __syncthreads();
    for (int i = seg_beg + tid; i < seg_end; i += 256) {
        unsigned u = ebuf[i];
        int pos = atomicAdd(&lcur[u >> 16], 1);
        csrc[seg_beg + pos] = (int)(u & 0xffffu);
    }
}

// ---------------- weight prep: bf16 transposed layouts ----------------
__global__ void cvt_x_kernel(const float* __restrict__ x, bf16* __restrict__ xb) {
    long i = (long)blockIdx.x * 256 + threadIdx.x;
    if (i < (long)NN * IND) ((short*)xb)[i] = f2bf_bits(x[i]);
}
// wT[64][K]: wT[m*K+k] = W[k*M+m]  (zero rows m>=M)
__global__ void prep_wT_kernel(const float* __restrict__ W, bf16* __restrict__ wT, int K, int M) {
    int idx = blockIdx.x * 256 + threadIdx.x;
    if (idx >= 64 * K) return;
    int m = idx / K, k = idx % K;
    ((short*)wT)[idx] = (m < M) ? f2bf_bits(W[(long)k * M + m]) : (short)0;
}
// GAT: wgT[64][512]: wgT[m*512 + (h*64+c)] = W[c*(8C)+h*C+m]  (zero m>=C)
template<int C>
__global__ void prep_wgT_kernel(const float* __restrict__ W, bf16* __restrict__ wgT) {
    int idx = blockIdx.x * 256 + threadIdx.x;
    if (idx >= 64 * 512) return;
    int m = idx >> 9, k = idx & 511;
    int h = k >> 6, c = k & 63;
    ((short*)wgT)[idx] = (m < C) ? f2bf_bits(W[(long)c * (NH * C) + h * C + m]) : (short)0;
}
// was[h*64+c] = sum_c' W[c][h*C+c'] * a[h*C+c']
template<int C>
__global__ void proj_aw_kernel(const float* __restrict__ W, const float* __restrict__ as,
        const float* __restrict__ ad, float* __restrict__ was, float* __restrict__ wad) {
    int idx = blockIdx.x * 256 + threadIdx.x;
    if (idx >= 512) return;
    int h = idx >> 6, c = idx & 63;
    const float* wrow = W + (long)c * (NH * C) + h * C;
    float s = 0.f, d = 0.f;
    for (int cc = 0; cc < C; ++cc) {
        float w = wrow[cc];
        s += w * as[h * C + cc];
        d += w * ad[h * C + cc];
    }
    was[idx] = s; wad[idx] = d;
}

// ---------------- MFMA matmul v2: NO LDS, fragments direct from global ----------------
// C[n,M] = A[n,K] @ WT^T where WT is [64][K] bf16 (rows >= M zeroed).
// A-frag: lane(lr,q) loads A[row0+rw+lr][k0+q*8] (16B, wave covers 16 full 64B lines).
// B-frag: wT[c*16+lr][k0+q*8] (L2-resident). No barriers, no bank conflicts.
// EPI 0: fp32; 2: bf16 relu(v*0.125+bias[col]); 3: bf16 rowscale[row]*v.
template<int K, int EPI>
__global__ __launch_bounds__(256) void mm2_kernel(const bf16* __restrict__ A,
        const bf16* __restrict__ wT, void* __restrict__ C,
        const float* __restrict__ bias, const float* __restrict__ rowscale,
        int nrows, int M) {
    const int row0 = blockIdx.x * 64;
    const int tid = threadIdx.x;
    const int lane = tid & 63, wave = tid >> 6;
    const int lr = lane & 15, q = lane >> 4;
    const int row = row0 + wave * 16 + lr;
    const bool rok = row < nrows;
    const short* ap = (const short*)A + (long)row * K + q * 8;
    floatx4 acc[4] = {};
#pragma unroll 4
    for (int k0 = 0; k0 < K; k0 += 32) {
        short8 av = {0, 0, 0, 0, 0, 0, 0, 0};
        if (rok) av = *(const short8*)(ap + k0);
        bf16x8 a = __builtin_bit_cast(bf16x8, av);
#pragma unroll
        for (int c = 0; c < 4; ++c) {
            bf16x8 b = __builtin_bit_cast(bf16x8,
                *(const short8*)((const short*)wT + (long)(c * 16 + lr) * K + k0 + q * 8));
            acc[c] = __builtin_amdgcn_mfma_f32_16x16x32_bf16(a, b, acc[c], 0, 0, 0);
        }
    }
#pragma unroll
    for (int c = 0; c < 4; ++c)
#pragma unroll
        for (int r = 0; r < 4; ++r) {
            int orow = row0 + wave * 16 + q * 4 + r;
            int col = c * 16 + lr;
            if (orow < nrows && col < M) {
                long o = (long)orow * M + col;
                float v = acc[c][r];
                if (EPI == 0) ((float*)C)[o] = v;
                else if (EPI == 2) {
                    v = v * 0.125f + bias[col];
                    ((bf16*)C)[o] = __float2bfloat16(fmaxf(v, 0.f));
                } else {
                    ((bf16*)C)[o] = __float2bfloat16(rowscale[orow] * v);
                }
            }
        }
}

// ---------------- fused GCN aggregate + bias + BN + ReLU ----------------
__global__ __launch_bounds__(256) void gcn_fused_kernel(const int* __restrict__ rowptr,
        const int* __restrict__ csrc, const float* __restrict__ dinv,
        const bf16* __restrict__ hin, const float* __restrict__ b,
        const float* __restrict__ gamma, const float* __restrict__ beta,
        const float* __restrict__ mean, const float* __restrict__ var,
        bf16* __restrict__ actout) {
    const int node = blockIdx.x * 4 + (threadIdx.x >> 6);
    if (node >= NN) return;
    const int lane = threadIdx.x & 63;
    const int beg = rowptr[node], end = rowptr[node + 1];
    const float di = dinv[node];
    float acc = bf2f(hin[(long)node * 64 + lane]);
    int ei = beg;
    for (; ei + 4 <= end; ei += 4) {
        int s0 = csrc[ei], s1 = csrc[ei + 1], s2 = csrc[ei + 2], s3 = csrc[ei + 3];
        float h0 = bf2f(hin[(long)s0 * 64 + lane]);
        float h1 = bf2f(hin[(long)s1 * 64 + lane]);
        float h2 = bf2f(hin[(long)s2 * 64 + lane]);
        float h3 = bf2f(hin[(long)s3 * 64 + lane]);
        acc += (h0 + h1) + (h2 + h3);
    }
    for (; ei < end; ++ei) {
        int s = csrc[ei];
        acc += bf2f(hin[(long)s * 64 + lane]);
    }
    float x = acc * di + b[lane];
    x = (x - mean[lane]) * rsqrtf(var[lane] + 1e-5f) * gamma[lane] + beta[lane];
    actout[(long)node * 64 + lane] = __float2bfloat16(fmaxf(x, 0.f));
}

// es[n,h] = <act[n,:], was[h,:]> — wave per node, lanes=(h=lane>>3, cg=lane&7)
__global__ __launch_bounds__(256) void scores_kernel(const bf16* __restrict__ actb,
        const float* __restrict__ was, const float* __restrict__ wad,
        float* __restrict__ es, float* __restrict__ ed, int n) {
    const int node = blockIdx.x * 4 + (threadIdx.x >> 6);
    if (node >= n) return;
    const int lane = threadIdx.x & 63;
    const int h = lane >> 3, cg = lane & 7;
    short8 a8 = *(const short8*)((const short*)actb + (long)node * 64 + cg * 8);
    const float* wsp = was + h * 64 + cg * 8;
    const float* wdp = wad + h * 64 + cg * 8;
    floatx4 ws0 = *(const floatx4*)wsp, ws1 = *(const floatx4*)(wsp + 4);
    floatx4 wd0 = *(const floatx4*)wdp, wd1 = *(const floatx4*)(wdp + 4);
    float s = 0.f, d = 0.f;
#pragma unroll
    for (int j = 0; j < 4; ++j) {
        float v0 = bf2f(__builtin_bit_cast(bf16, a8[j]));
        float v1 = bf2f(__builtin_bit_cast(bf16, a8[4 + j]));
        s += v0 * ws0[j] + v1 * ws1[j];
        d += v0 * wd0[j] + v1 * wd1[j];
    }
#pragma unroll
    for (int off = 1; off < 8; off <<= 1) {
        s += __shfl_xor(s, off);
        d += __shfl_xor(d, off);
    }
    if (cg == 0) { es[node * NH + h] = s; ed[node * NH + h] = d; }
}

// ---------------- GAT aggregation (self-logit-shifted softmax, exact) ----------------
__global__ __launch_bounds__(256) void gat_agg_kernel(const int* __restrict__ rowptr,
        const int* __restrict__ csrc, const float* __restrict__ es, const float* __restrict__ ed,
        const bf16* __restrict__ actb, bf16* __restrict__ agg) {
    __shared__ __align__(16) float salpha[4][512];
    __shared__ int ssrcs[4][64];
    __shared__ __align__(16) float sself[4][8];
    const int wv = threadIdx.x >> 6;
    const int node = blockIdx.x * 4 + wv;
    if (node >= NN) return;
    const int lane = threadIdx.x & 63;
    const int h = lane & 7, slot = lane >> 3;
    const int beg = rowptr[node], end = rowptr[node + 1];
    const int deg = end - beg;
    const float edr = ed[node * NH + h];

    float selfe = es[node * NH + h] + edr;
    selfe = selfe > 0.f ? selfe : 0.2f * selfe;

    float acc[NH] = {0.f, 0.f, 0.f, 0.f, 0.f, 0.f, 0.f, 0.f};

    if (deg <= 64) {
        float ex_r[8]; int s_r[8];
        float den = 0.f;
#pragma unroll
        for (int b = 0; b < 8; ++b) {
            ex_r[b] = 0.f; s_r[b] = 0;
            int k = b * 8 + slot;
            if (k < deg) {
                int s = csrc[beg + k];
                s_r[b] = s;
                float e = es[s * NH + h] + edr;
                e = e > 0.f ? e : 0.2f * e;
                ex_r[b] = __expf(e - selfe);
                den += ex_r[b];
            }
        }
        den += __shfl_xor(den, 8);
        den += __shfl_xor(den, 16);
        den += __shfl_xor(den, 32);
        const float invden = 1.f / (den + 1.f);

#pragma unroll
        for (int b = 0; b < 8; ++b)
            salpha[wv][b * 64 + lane] = ex_r[b] * invden;
        if (h == 0) {
#pragma unroll
            for (int b = 0; b < 8; ++b)
                ssrcs[wv][b * 8 + slot] = s_r[b];
        }
        if (slot == 0) sself[wv][h] = invden;

#pragma unroll 4
        for (int k = 0; k < deg; ++k) {
            int s = ssrcs[wv][k];
            float a = bf2f(actb[(long)s * 64 + lane]);
            const float* ap = &salpha[wv][(k >> 3) * 64 + (k & 7) * 8];
            floatx4 al0 = *(const floatx4*)ap;
            floatx4 al1 = *(const floatx4*)(ap + 4);
            acc[0] += al0[0] * a; acc[1] += al0[1] * a;
            acc[2] += al0[2] * a; acc[3] += al0[3] * a;
            acc[4] += al1[0] * a; acc[5] += al1[1] * a;
            acc[6] += al1[2] * a; acc[7] += al1[3] * a;
        }
        {
            float a = bf2f(actb[(long)node * 64 + lane]);
            floatx4 s0 = *(const floatx4*)&sself[wv][0];
            floatx4 s1 = *(const floatx4*)&sself[wv][4];
            acc[0] += s0[0] * a; acc[1] += s0[1] * a;
            acc[2] += s0[2] * a; acc[3] += s0[3] * a;
            acc[4] += s1[0] * a; acc[5] += s1[1] * a;
            acc[6] += s1[2] * a; acc[7] += s1[3] * a;
        }
    } else {
        float den = 0.f;
        for (int base = beg; base < end; base += 8) {
            int ei = base + slot;
            if (ei < end) {
                int s = csrc[ei];
                float e = es[s * NH + h] + edr;
                e = e > 0.f ? e : 0.2f * e;
                den += __expf(e - selfe);
            }
        }
        den += __shfl_xor(den, 8);
        den += __shfl_xor(den, 16);
        den += __shfl_xor(den, 32);
        const float invden = 1.f / (den + 1.f);
        for (int base = beg; base < end; base += 8) {
            int ei = base + slot;
            float al = 0.f; int sl = 0;
            if (ei < end) {
                sl = csrc[ei];
                float e = es[sl * NH + h] + edr;
                e = e > 0.f ? e : 0.2f * e;
                al = __expf(e - selfe) * invden;
            }
            salpha[wv][lane] = al;
            if (h == 0) ssrcs[wv][slot] = sl;
            int ecnt = end - base; if (ecnt > 8) ecnt = 8;
            for (int j = 0; j < ecnt; ++j) {
                int s = ssrcs[wv][j];
                float a = bf2f(actb[(long)s * 64 + lane]);
                floatx4 al0 = *(const floatx4*)&salpha[wv][j * 8];
                floatx4 al1 = *(const floatx4*)&salpha[wv][j * 8 + 4];
                acc[0] += al0[0] * a; acc[1] += al0[1] * a;
                acc[2] += al0[2] * a; acc[3] += al0[3] * a;
                acc[4] += al1[0] * a; acc[5] += al1[1] * a;
                acc[6] += al1[2] * a; acc[7] += al1[3] * a;
            }
        }
        {
            if (slot == 0) sself[wv][h] = invden;
            float a = bf2f(actb[(long)node * 64 + lane]);
            floatx4 s0 = *(const floatx4*)&sself[wv][0];
            floatx4 s1 = *(const floatx4*)&sself[wv][4];
            acc[0] += s0[0] * a; acc[1] += s0[1] * a;
            acc[2] += s0[2] * a; acc[3] += s0[3] * a;
            acc[4] += s1[0] * a; acc[5] += s1[1] * a;
            acc[6] += s1[2] * a; acc[7] += s1[3] * a;
        }
    }
#pragma unroll
    for (int hh = 0; hh < NH; ++hh)
        agg[(long)node * 512 + hh * 64 + lane] = __float2bfloat16(acc[hh]);
}

// ---------------- final log_softmax (32 cols) ----------------
__global__ __launch_bounds__(256) void logsoftmax_kernel(const float* __restrict__ acc,
        const float* __restrict__ b, float* __restrict__ out, int n) {
    int idx = blockIdx.x * 256 + threadIdx.x;
    int nd = idx >> 5, lane = idx & 31;
    if (nd >= n) return;
    float v = acc[idx] * 0.125f + b[lane];
    float m = v;
    for (int off = 16; off; off >>= 1) m = fmaxf(m, __shfl_xor(m, off, 32));
    float exv = __expf(v - m);
    float ssum = exv;
    for (int off = 16; off; off >>= 1) ssum += __shfl_xor(ssum, off, 32);
    out[idx] = v - m - logf(ssum);
}

// ---------------- launch ----------------
extern "C" void kernel_launch(void* const* d_in, const int* in_sizes, int n_in,
                              void* d_out, int out_size, void* d_ws, size_t ws_size,
                              hipStream_t stream) {
    const float* x        = (const float*)d_in[0];
    const int*   eidx     = (const int*)d_in[1];
    const float* gcn1_w   = (const float*)d_in[2];
    const float* gcn1_b   = (const float*)d_in[3];
    const float* bn1_g    = (const float*)d_in[4];
    const float* bn1_b    = (const float*)d_in[5];
    const float* bn1_m    = (const float*)d_in[6];
    const float* bn1_v    = (const float*)d_in[7];
    const float* gat1_w   = (const float*)d_in[8];
    const float* gat1_as  = (const float*)d_in[9];
    const float* gat1_ad  = (const float*)d_in[10];
    const float* gat1_b   = (const float*)d_in[11];
    const float* gcn2_w   = (const float*)d_in[12];
    const float* gcn2_b   = (const float*)d_in[13];
    const float* bn2_g    = (const float*)d_in[14];
    const float* bn2_b    = (const float*)d_in[15];
    const float* bn2_m    = (const float*)d_in[16];
    const float* bn2_v    = (const float*)d_in[17];
    const float* gat2_w   = (const float*)d_in[18];
    const float* gat2_as  = (const float*)d_in[19];
    const float* gat2_ad  = (const float*)d_in[20];
    const float* gat2_b   = (const float*)d_in[21];
    float* out = (float*)d_out;

    const int* esrc = eidx;
    const int* edst = eidx + NE;

    // workspace (~98 MB, < proven-safe 110.6 MB)
    float* ws = (float*)d_ws;
    int*      ghist  = (int*)ws;                        // GH
    int*      gpre   = ghist + GH;                      // GH
    int*      gbsum  = gpre + GH;                       // 512
    unsigned* ebuf   = (unsigned*)(gbsum + 512);        // NE
    int*      rowptr = (int*)(ebuf + NE);               // 50048
    int*      csrc   = rowptr + 50048;                  // NE
    float*    dinv   = (float*)(csrc + NE);             // 50048
    float*    es     = dinv + 50048;                    // 400000
    float*    ed     = es + 400000;                     // 400000
    float*    was    = ed + 400000;                     // 512
    float*    wad    = was + 512;                       // 512
    float*    buf32  = wad + 512;                       // N*32 f32
    bf16*     wT1    = (bf16*)(buf32 + (size_t)NN * 32);// 64*128
    bf16*     wT2    = wT1 + 64 * 128;                  // 64*64
    bf16*     wgT1   = wT2 + 64 * 64;                   // 64*512
    bf16*     wgT2   = wgT1 + 64 * 512;                 // 64*512
    bf16*     xb     = wgT2 + 64 * 512;                 // N*128 bf16
    bf16*     actb   = xb + (size_t)NN * IND;           // N*64 bf16
    bf16*     mmbf   = actb + (size_t)NN * 64;          // N*64 bf16
    bf16*     agg    = mmbf + (size_t)NN * 64;          // N*512 bf16

    auto cdiv = [](long a, long b) { return (int)((a + b - 1) / b); };
    const int GB = cdiv(NN, 64);       // 782 row-blocks
    const int NB = cdiv(NN, 4);        // 12500 node-blocks

    // ---- CSR build ----
    bin_count_kernel<<<EBLK, 256, 0, stream>>>(edst, ghist);
    scang1_kernel<<<GH / 256, 256, 0, stream>>>(ghist, gpre, gbsum, GH);
    scang2_kernel<<<1, 512, 0, stream>>>(gbsum, GH / 256);
    scang3_kernel<<<GH / 256, 256, 0, stream>>>(gpre, gbsum, ghist, GH);
    bin_scatter_kernel<<<EBLK, 256, 0, stream>>>(esrc, edst, ghist, ebuf);
    bucket_finalize_kernel<<<NBUK, 256, 0, stream>>>(ebuf, ghist, rowptr, dinv, csrc);

    // ---- weight/input prep (bf16 transposed) ----
    cvt_x_kernel<<<cdiv((long)NN * IND, 256), 256, 0, stream>>>(x, xb);
    prep_wT_kernel<<<cdiv(64 * 128, 256), 256, 0, stream>>>(gcn1_w, wT1, 128, 64);
    prep_wT_kernel<<<cdiv(64 * 64, 256), 256, 0, stream>>>(gcn2_w, wT2, 64, 64);
    prep_wgT_kernel<64><<<cdiv(64 * 512, 256), 256, 0, stream>>>(gat1_w, wgT1);
    prep_wgT_kernel<32><<<cdiv(64 * 512, 256), 256, 0, stream>>>(gat2_w, wgT2);
    proj_aw_kernel<64><<<2, 256, 0, stream>>>(gat1_w, gat1_as, gat1_ad, was, wad);

    // ---- GCN1 ----
    mm2_kernel<IND, 3><<<GB, 256, 0, stream>>>(xb, wT1, mmbf, nullptr, dinv, NN, 64);
    gcn_fused_kernel<<<NB, 256, 0, stream>>>(rowptr, csrc, dinv, mmbf,
        gcn1_b, bn1_g, bn1_b, bn1_m, bn1_v, actb);

    // ---- GAT1 (C=64) ----
    scores_kernel<<<NB, 256, 0, stream>>>(actb, was, wad, es, ed, NN);
    gat_agg_kernel<<<NB, 256, 0, stream>>>(rowptr, csrc, es, ed, actb, agg);
    mm2_kernel<512, 2><<<GB, 256, 0, stream>>>(agg, wgT1, actb, gat1_b, nullptr, NN, 64);

    // ---- GCN2 ----
    mm2_kernel<64, 3><<<GB, 256, 0, stream>>>(actb, wT2, mmbf, nullptr, dinv, NN, 64);
    gcn_fused_kernel<<<NB, 256, 0, stream>>>(rowptr, csrc, dinv, mmbf,
        gcn2_b, bn2_g, bn2_b, bn2_m, bn2_v, actb);

    // ---- GAT2 (C=32) ----
    proj_aw_kernel<32><<<2, 256, 0, stream>>>(gat2_w, gat2_as, gat2_ad, was, wad);
    scores_kernel<<<NB, 256, 0, stream>>>(actb, was, wad, es, ed, NN);
    gat_agg_kernel<<<NB, 256, 0, stream>>>(rowptr, csrc, es, ed, actb, agg);
    mm2_kernel<512, 0><<<GB, 256, 0, stream>>>(agg, wgT2, buf32, nullptr, nullptr, NN, 32);

    // ---- log_softmax -> fp32 out ----
    logsoftmax_kernel<<<cdiv((long)NN * 32, 256), 256, 0, stream>>>(buf32, gat2_b, out, NN);
}